// Round 1
// baseline (428.823 us; speedup 1.0000x reference)
//
#include <hip/hip_runtime.h>
#include <hip/hip_bf16.h>

#define B_    32
#define T_    256
#define C_    512
#define H_    512
#define TOUT_ 2048
#define EPS_  1e-5f

// ---------------------------------------------------------------------------
// 1) inclusive cumsum of durations, one block per batch row (Hillis-Steele)
// ---------------------------------------------------------------------------
__global__ __launch_bounds__(256) void csum_kernel(const int* __restrict__ dur,
                                                   int* __restrict__ csum) {
  __shared__ int s[256];
  const int b = blockIdx.x, tid = threadIdx.x;
  s[tid] = dur[b * T_ + tid];
  __syncthreads();
#pragma unroll
  for (int off = 1; off < 256; off <<= 1) {
    int v = (tid >= off) ? s[tid - off] : 0;
    __syncthreads();
    s[tid] += v;
    __syncthreads();
  }
  csum[b * T_ + tid] = s[tid];
}

// ---------------------------------------------------------------------------
// 2) expand-by-durations gather: each block handles 8 output rows of one batch
// ---------------------------------------------------------------------------
__global__ __launch_bounds__(256) void expand_kernel(const float* __restrict__ X,
                                                     const int* __restrict__ csum,
                                                     float* __restrict__ out) {
  __shared__ int sc[256];
  __shared__ int sidx[8];
  const int tid = threadIdx.x;
  const int chunks = TOUT_ / 8;                 // 256
  const int b  = blockIdx.x / chunks;
  const int t0 = (blockIdx.x % chunks) * 8;

  sc[tid] = csum[b * T_ + tid];
  __syncthreads();
  const int total = sc[T_ - 1];
  if (tid < 8) {
    const int pos = t0 + tid;
    // first i with csum[i] > pos  (searchsorted side='right')
    int l = 0, r = T_;
    while (l < r) { int m = (l + r) >> 1; if (sc[m] > pos) r = m; else l = m + 1; }
    sidx[tid] = (pos < total) ? min(l, T_ - 1) : -1;
  }
  __syncthreads();

  const int half = tid >> 7;     // 0/1 : two rows processed per pass
  const int c4   = tid & 127;    // 128 float4 per 512-float row
  const float4 z = make_float4(0.f, 0.f, 0.f, 0.f);
#pragma unroll
  for (int rr = half; rr < 8; rr += 2) {
    const int idx = sidx[rr];
    float4 v = z;
    if (idx >= 0)
      v = *(const float4*)(X + (size_t)(b * T_ + idx) * C_ + c4 * 4);
    *(float4*)(out + (size_t)(b * TOUT_ + t0 + rr) * C_ + c4 * 4) = v;
  }
}

// ---------------------------------------------------------------------------
// 3) conv1d(k=3,'SAME') as implicit-im2col GEMM:
//    Y[m,n] = sum_k A[m,k]*W[k,n] + bias[n]
//    M=8192 (b*T+t), K=1536 (kw*512+c), N=512. W is [3,Cin,H] row-major = [1536,512].
//    64x64 block tile, 4x4 per thread, BK=16, f32 FMA.
// ---------------------------------------------------------------------------
#define FMA4(i, ax)                                   \
  acc[i][0] = fmaf(ax, bv4.x, acc[i][0]);             \
  acc[i][1] = fmaf(ax, bv4.y, acc[i][1]);             \
  acc[i][2] = fmaf(ax, bv4.z, acc[i][2]);             \
  acc[i][3] = fmaf(ax, bv4.w, acc[i][3]);

__global__ __launch_bounds__(256) void conv_gemm_kernel(const float* __restrict__ X,
                                                        const float* __restrict__ W,
                                                        const float* __restrict__ bias,
                                                        float* __restrict__ Y) {
  __shared__ float As[16][64];   // [k][m] — b128 broadcast reads in inner loop
  __shared__ float Bs[16][64];   // [k][n] — linear float4 writes / 2-way-free reads

  const int tid = threadIdx.x;
  const int m0 = blockIdx.y * 64;
  const int n0 = blockIdx.x * 64;
  const int ty = tid >> 4;       // 0..15 -> m group
  const int tx = tid & 15;       // 0..15 -> n group

  float acc[4][4] = {};

  // A-tile load indices: thread loads float4 of 4 consecutive k for one m
  const int am   = m0 + (tid >> 2);
  const int kofs = (tid & 3) << 2;
  const int t    = am & (T_ - 1);
  const int mm   = tid >> 2;
  // B-tile load indices: thread loads float4 of 4 consecutive n for one k
  const int bkk = tid >> 4;
  const int bnn = (tid & 15) << 2;

  for (int k0 = 0; k0 < 1536; k0 += 16) {
    const int k  = k0 + kofs;
    const int kw = k >> 9;
    const int c  = k & 511;
    const int st = t + kw - 1;
    float4 av = make_float4(0.f, 0.f, 0.f, 0.f);
    if (st >= 0 && st < T_)
      av = *(const float4*)(X + (size_t)(am + kw - 1) * C_ + c);
    As[kofs + 0][mm] = av.x;
    As[kofs + 1][mm] = av.y;
    As[kofs + 2][mm] = av.z;
    As[kofs + 3][mm] = av.w;

    const float4 bv = *(const float4*)(W + (size_t)(k0 + bkk) * H_ + n0 + bnn);
    *(float4*)&Bs[bkk][bnn] = bv;
    __syncthreads();

#pragma unroll
    for (int kk = 0; kk < 16; ++kk) {
      const float4 av4 = *(const float4*)&As[kk][ty * 4];
      const float4 bv4 = *(const float4*)&Bs[kk][tx * 4];
      FMA4(0, av4.x)
      FMA4(1, av4.y)
      FMA4(2, av4.z)
      FMA4(3, av4.w)
    }
    __syncthreads();
  }

  const float4 bb = *(const float4*)(bias + n0 + tx * 4);
#pragma unroll
  for (int i = 0; i < 4; ++i) {
    float4 o;
    o.x = acc[i][0] + bb.x;
    o.y = acc[i][1] + bb.y;
    o.z = acc[i][2] + bb.z;
    o.w = acc[i][3] + bb.w;
    *(float4*)(Y + (size_t)(m0 + ty * 4 + i) * H_ + n0 + tx * 4) = o;
  }
}

// ---------------------------------------------------------------------------
// 4) LayerNorm + ReLU, one wave per 512-float row (no block sync needed)
// ---------------------------------------------------------------------------
__global__ __launch_bounds__(256) void ln_relu_kernel(const float* __restrict__ in,
                                                      const float* __restrict__ g,
                                                      const float* __restrict__ beta,
                                                      float* __restrict__ out) {
  const int wave = threadIdx.x >> 6;
  const int lane = threadIdx.x & 63;
  const int row  = blockIdx.x * 4 + wave;
  const float* r = in + (size_t)row * H_;

  const float4 v0 = *(const float4*)(r + lane * 4);
  const float4 v1 = *(const float4*)(r + 256 + lane * 4);

  float s = v0.x + v0.y + v0.z + v0.w + v1.x + v1.y + v1.z + v1.w;
  float q = v0.x * v0.x + v0.y * v0.y + v0.z * v0.z + v0.w * v0.w +
            v1.x * v1.x + v1.y * v1.y + v1.z * v1.z + v1.w * v1.w;
#pragma unroll
  for (int off = 32; off; off >>= 1) {
    s += __shfl_xor(s, off);
    q += __shfl_xor(q, off);
  }
  const float mu  = s * (1.0f / 512.0f);
  const float var = q * (1.0f / 512.0f) - mu * mu;
  const float rs  = rsqrtf(var + EPS_);

  const float4 g0 = *(const float4*)(g + lane * 4);
  const float4 g1 = *(const float4*)(g + 256 + lane * 4);
  const float4 e0 = *(const float4*)(beta + lane * 4);
  const float4 e1 = *(const float4*)(beta + 256 + lane * 4);

  float4 o0, o1;
  o0.x = fmaxf(0.f, (v0.x - mu) * rs * g0.x + e0.x);
  o0.y = fmaxf(0.f, (v0.y - mu) * rs * g0.y + e0.y);
  o0.z = fmaxf(0.f, (v0.z - mu) * rs * g0.z + e0.z);
  o0.w = fmaxf(0.f, (v0.w - mu) * rs * g0.w + e0.w);
  o1.x = fmaxf(0.f, (v1.x - mu) * rs * g1.x + e1.x);
  o1.y = fmaxf(0.f, (v1.y - mu) * rs * g1.y + e1.y);
  o1.z = fmaxf(0.f, (v1.z - mu) * rs * g1.z + e1.z);
  o1.w = fmaxf(0.f, (v1.w - mu) * rs * g1.w + e1.w);

  float* w = out + (size_t)row * H_;
  *(float4*)(w + lane * 4)       = o0;
  *(float4*)(w + 256 + lane * 4) = o1;
}

// ---------------------------------------------------------------------------
// 5) linear head: one wave per row, dot(h_row, Wl) + bl
// ---------------------------------------------------------------------------
__global__ __launch_bounds__(256) void linear_kernel(const float* __restrict__ Hin,
                                                     const float* __restrict__ Wl,
                                                     const float* __restrict__ bl,
                                                     float* __restrict__ out) {
  const int wave = threadIdx.x >> 6;
  const int lane = threadIdx.x & 63;
  const int row  = blockIdx.x * 4 + wave;
  const float* r = Hin + (size_t)row * H_;

  const float4 v0 = *(const float4*)(r + lane * 4);
  const float4 v1 = *(const float4*)(r + 256 + lane * 4);
  const float4 w0 = *(const float4*)(Wl + lane * 4);
  const float4 w1 = *(const float4*)(Wl + 256 + lane * 4);

  float s = v0.x * w0.x + v0.y * w0.y + v0.z * w0.z + v0.w * w0.w +
            v1.x * w1.x + v1.y * w1.y + v1.z * w1.z + v1.w * w1.w;
#pragma unroll
  for (int off = 32; off; off >>= 1) s += __shfl_xor(s, off);

  if (lane == 0) out[row] = s + bl[0];
}

// ---------------------------------------------------------------------------
extern "C" void kernel_launch(void* const* d_in, const int* in_sizes, int n_in,
                              void* d_out, int out_size, void* d_ws, size_t ws_size,
                              hipStream_t stream) {
  const float* x     = (const float*)d_in[0];
  const int*   dur   = (const int*)d_in[1];
  const float* W1    = (const float*)d_in[2];
  const float* b1    = (const float*)d_in[3];
  const float* g1    = (const float*)d_in[4];
  const float* beta1 = (const float*)d_in[5];
  const float* W2    = (const float*)d_in[6];
  const float* b2    = (const float*)d_in[7];
  const float* g2    = (const float*)d_in[8];
  const float* beta2 = (const float*)d_in[9];
  const float* Wl    = (const float*)d_in[10];
  const float* bl    = (const float*)d_in[11];

  float* out = (float*)d_out;
  float* res    = out;                                  // [B, TOUT, C]
  float* loglen = out + (size_t)B_ * TOUT_ * C_;        // [B, T]

  char*  ws   = (char*)d_ws;
  int*   csum = (int*)ws;                               // 32 KB
  float* tmp1 = (float*)(ws + 32768);                   // [B*T, H] f32
  float* tmp2 = tmp1 + (size_t)B_ * T_ * H_;            // [B*T, H] f32

  csum_kernel<<<B_, 256, 0, stream>>>(dur, csum);
  expand_kernel<<<B_ * TOUT_ / 8, 256, 0, stream>>>(x, csum, res);

  conv_gemm_kernel<<<dim3(H_ / 64, B_ * T_ / 64), 256, 0, stream>>>(x, W1, b1, tmp1);
  ln_relu_kernel<<<B_ * T_ / 4, 256, 0, stream>>>(tmp1, g1, beta1, tmp2);
  conv_gemm_kernel<<<dim3(H_ / 64, B_ * T_ / 64), 256, 0, stream>>>(tmp2, W2, b2, tmp1);
  ln_relu_kernel<<<B_ * T_ / 4, 256, 0, stream>>>(tmp1, g2, beta2, tmp2);
  linear_kernel<<<B_ * T_ / 4, 256, 0, stream>>>(tmp2, Wl, bl, loglen);
}

// Round 2
// 133.387 us; speedup vs baseline: 3.2149x; 3.2149x over previous
//
#include <hip/hip_runtime.h>
#include <hip/hip_bf16.h>

#define B_    32
#define T_    256
#define C_    512
#define H_    512
#define TOUT_ 2048
#define TP_   258        // padded time length (zero row at t=0 and t=257)
#define K_    1536       // 3 * 512
#define EPS_  1e-5f

typedef __attribute__((ext_vector_type(8))) short bf16x8;
typedef __attribute__((ext_vector_type(4))) float f32x4;

#define GLL16(g, l)                                                        \
  __builtin_amdgcn_global_load_lds(                                        \
      (const __attribute__((address_space(1))) void*)(g),                  \
      (__attribute__((address_space(3))) void*)(l), 16, 0, 0)

// ---------------------------------------------------------------------------
// 1) inclusive cumsum of durations, one block per batch row
// ---------------------------------------------------------------------------
__global__ __launch_bounds__(256) void csum_kernel(const int* __restrict__ dur,
                                                   int* __restrict__ csum) {
  __shared__ int s[256];
  const int b = blockIdx.x, tid = threadIdx.x;
  s[tid] = dur[b * T_ + tid];
  __syncthreads();
#pragma unroll
  for (int off = 1; off < 256; off <<= 1) {
    int v = (tid >= off) ? s[tid - off] : 0;
    __syncthreads();
    s[tid] += v;
    __syncthreads();
  }
  csum[b * T_ + tid] = s[tid];
}

// ---------------------------------------------------------------------------
// 2) expand-by-durations gather (exact f32 path)
// ---------------------------------------------------------------------------
__global__ __launch_bounds__(256) void expand_kernel(const float* __restrict__ X,
                                                     const int* __restrict__ csum,
                                                     float* __restrict__ out) {
  __shared__ int sc[256];
  __shared__ int sidx[8];
  const int tid = threadIdx.x;
  const int chunks = TOUT_ / 8;                 // 256
  const int b  = blockIdx.x / chunks;
  const int t0 = (blockIdx.x % chunks) * 8;

  sc[tid] = csum[b * T_ + tid];
  __syncthreads();
  const int total = sc[T_ - 1];
  if (tid < 8) {
    const int pos = t0 + tid;
    int l = 0, r = T_;
    while (l < r) { int m = (l + r) >> 1; if (sc[m] > pos) r = m; else l = m + 1; }
    sidx[tid] = (pos < total) ? min(l, T_ - 1) : -1;
  }
  __syncthreads();

  const int half = tid >> 7;
  const int c4   = tid & 127;
  const float4 z = make_float4(0.f, 0.f, 0.f, 0.f);
#pragma unroll
  for (int rr = half; rr < 8; rr += 2) {
    const int idx = sidx[rr];
    float4 v = z;
    if (idx >= 0)
      v = *(const float4*)(X + (size_t)(b * T_ + idx) * C_ + c4 * 4);
    *(float4*)(out + (size_t)(b * TOUT_ + t0 + rr) * C_ + c4 * 4) = v;
  }
}

// ---------------------------------------------------------------------------
// 3) convert x (f32) -> padded bf16 [32][258][512]; also zero pad rows of hpad
// ---------------------------------------------------------------------------
__global__ __launch_bounds__(128) void cvt_x_pad_kernel(const float* __restrict__ X,
                                                        __hip_bfloat16* __restrict__ xpad,
                                                        __hip_bfloat16* __restrict__ hpad) {
  const int row = blockIdx.x;           // 0 .. 32*258-1
  const int b = row / TP_;
  const int t = row - b * TP_;
  const int c = threadIdx.x * 4;
  __hip_bfloat16* dst = xpad + (size_t)row * C_ + c;
  if (t == 0 || t == TP_ - 1) {
    ushort4 zz = make_ushort4(0, 0, 0, 0);
    *(ushort4*)dst = zz;
    *(ushort4*)(hpad + (size_t)row * C_ + c) = zz;
    return;
  }
  const float4 v = *(const float4*)(X + (size_t)(b * T_ + t - 1) * C_ + c);
  union { __hip_bfloat16 h[4]; ushort4 u; } o;
  o.h[0] = __float2bfloat16(v.x);
  o.h[1] = __float2bfloat16(v.y);
  o.h[2] = __float2bfloat16(v.z);
  o.h[3] = __float2bfloat16(v.w);
  *(ushort4*)dst = o.u;
}

// ---------------------------------------------------------------------------
// 4) weight transpose+convert: W [1536][512] f32 -> Wt [512][1536] bf16
//    grid.z selects (W1->Wt1) / (W2->Wt2)
// ---------------------------------------------------------------------------
__global__ __launch_bounds__(256) void cvt_wt_kernel(const float* __restrict__ W1,
                                                     const float* __restrict__ W2,
                                                     __hip_bfloat16* __restrict__ Wt1,
                                                     __hip_bfloat16* __restrict__ Wt2) {
  __shared__ float tile[32][33];
  const float* W = blockIdx.z ? W2 : W1;
  __hip_bfloat16* Wt = blockIdx.z ? Wt2 : Wt1;
  const int k0 = blockIdx.x * 32;       // 48 blocks
  const int n0 = blockIdx.y * 32;       // 16 blocks
  const int tx = threadIdx.x & 31;
  const int ty = threadIdx.x >> 5;      // 0..7
#pragma unroll
  for (int i = 0; i < 4; ++i)
    tile[ty * 4 + i][tx] = W[(size_t)(k0 + ty * 4 + i) * H_ + n0 + tx];
  __syncthreads();
#pragma unroll
  for (int i = 0; i < 4; ++i)
    Wt[(size_t)(n0 + ty * 4 + i) * K_ + k0 + tx] =
        __float2bfloat16(tile[tx][ty * 4 + i]);
}

// ---------------------------------------------------------------------------
// 5) conv1d(k=3) as bf16 MFMA GEMM. M=8192, K=1536, N=512.
//    128x128 tile, BK=32, 4 waves (2x2), each 64x64 = 4x4 mfma_16x16x32 frags.
//    LDS layout per tile: [kgrp=4][row=128][8] bf16 (conflict-free b128 reads).
//    Double-buffered, global_load_lds width-16 staging.
// ---------------------------------------------------------------------------
__global__ __launch_bounds__(256) void conv_mfma_kernel(
    const __hip_bfloat16* __restrict__ Apad,   // [32*258, 512]
    const __hip_bfloat16* __restrict__ Wt,     // [512, 1536]
    const float* __restrict__ bias,            // [512]
    float* __restrict__ Y) {                   // [8192, 512]
  __shared__ __hip_bfloat16 sm[2][2][4096];    // [buf][A/B][4*128*8] = 32 KB

  const int tid  = threadIdx.x;
  const int lane = tid & 63;
  const int wid  = tid >> 6;
  const int m0 = blockIdx.y << 7;
  const int n0 = blockIdx.x << 7;
  const int b  = m0 >> 8;
  const int t0 = m0 & 255;
  const int wm = (wid >> 1) << 6;
  const int wn = (wid & 1) << 6;

  // staging coords: thread covers slab g0 (and g0+2), row rr, 8 k-elements
  const int g0 = tid >> 7;              // 0/1
  const int rr = tid & 127;
  const __hip_bfloat16* arow = Apad + (size_t)(b * TP_ + t0 + rr) * C_;
  const __hip_bfloat16* brow = Wt + (size_t)(n0 + rr) * K_;

  f32x4 acc[4][4] = {};

  auto stage = [&](int buf, int k0) {
    const int kw = k0 >> 9;             // 0..2
    const int c0 = k0 & 511;
    const __hip_bfloat16* as = arow + kw * C_ + c0 + (g0 << 3);
    __hip_bfloat16* ad = &sm[buf][0][(g0 << 10) + (rr << 3)];
    GLL16(as, ad);
    GLL16(as + 16, ad + 2048);          // k-slab g0+2
    const __hip_bfloat16* bs = brow + k0 + (g0 << 3);
    __hip_bfloat16* bd = &sm[buf][1][(g0 << 10) + (rr << 3)];
    GLL16(bs, bd);
    GLL16(bs + 16, bd + 2048);
  };

  auto compute = [&](int buf) {
    const __hip_bfloat16* As = sm[buf][0];
    const __hip_bfloat16* Bs = sm[buf][1];
    const int g   = lane >> 4;
    const int r15 = lane & 15;
    bf16x8 aF[4], bF[4];
#pragma unroll
    for (int i = 0; i < 4; ++i) {
      aF[i] = *(const bf16x8*)(As + (g << 10) + ((wm + (i << 4) + r15) << 3));
      bF[i] = *(const bf16x8*)(Bs + (g << 10) + ((wn + (i << 4) + r15) << 3));
    }
#pragma unroll
    for (int mi = 0; mi < 4; ++mi)
#pragma unroll
      for (int ni = 0; ni < 4; ++ni)
        acc[mi][ni] = __builtin_amdgcn_mfma_f32_16x16x32_bf16(
            aF[mi], bF[ni], acc[mi][ni], 0, 0, 0);
  };

  stage(0, 0);
  __syncthreads();
  int cur = 0;
  for (int k0 = 32; k0 < K_; k0 += 32) {
    stage(cur ^ 1, k0);
    compute(cur);
    __syncthreads();
    cur ^= 1;
  }
  compute(cur);

  // epilogue: C/D layout col=lane&15 (n), row=(lane>>4)*4+reg (m)
  const int cn_base = n0 + wn + (lane & 15);
  const int rm_base = m0 + wm + ((lane >> 4) << 2);
#pragma unroll
  for (int ni = 0; ni < 4; ++ni) {
    const int cn = cn_base + (ni << 4);
    const float bb = bias[cn];
#pragma unroll
    for (int mi = 0; mi < 4; ++mi) {
#pragma unroll
      for (int rq = 0; rq < 4; ++rq) {
        const int rm = rm_base + (mi << 4) + rq;
        Y[(size_t)rm * H_ + cn] = acc[mi][ni][rq] + bb;
      }
    }
  }
}

// ---------------------------------------------------------------------------
// 6) LayerNorm + ReLU, f32 in -> bf16 out written into padded layout
// ---------------------------------------------------------------------------
__global__ __launch_bounds__(256) void ln_relu_pad_kernel(const float* __restrict__ in,
                                                          const float* __restrict__ g,
                                                          const float* __restrict__ beta,
                                                          __hip_bfloat16* __restrict__ outpad) {
  const int wave = threadIdx.x >> 6;
  const int lane = threadIdx.x & 63;
  const int row  = blockIdx.x * 4 + wave;   // 0..8191
  const float* r = in + (size_t)row * H_;

  const float4 v0 = *(const float4*)(r + lane * 4);
  const float4 v1 = *(const float4*)(r + 256 + lane * 4);

  float s = v0.x + v0.y + v0.z + v0.w + v1.x + v1.y + v1.z + v1.w;
  float q = v0.x * v0.x + v0.y * v0.y + v0.z * v0.z + v0.w * v0.w +
            v1.x * v1.x + v1.y * v1.y + v1.z * v1.z + v1.w * v1.w;
#pragma unroll
  for (int off = 32; off; off >>= 1) {
    s += __shfl_xor(s, off);
    q += __shfl_xor(q, off);
  }
  const float mu  = s * (1.0f / 512.0f);
  const float var = q * (1.0f / 512.0f) - mu * mu;
  const float rs  = rsqrtf(var + EPS_);

  const float4 g0 = *(const float4*)(g + lane * 4);
  const float4 g1 = *(const float4*)(g + 256 + lane * 4);
  const float4 e0 = *(const float4*)(beta + lane * 4);
  const float4 e1 = *(const float4*)(beta + 256 + lane * 4);

  union { __hip_bfloat16 h[4]; ushort4 u; } o0, o1;
  o0.h[0] = __float2bfloat16(fmaxf(0.f, (v0.x - mu) * rs * g0.x + e0.x));
  o0.h[1] = __float2bfloat16(fmaxf(0.f, (v0.y - mu) * rs * g0.y + e0.y));
  o0.h[2] = __float2bfloat16(fmaxf(0.f, (v0.z - mu) * rs * g0.z + e0.z));
  o0.h[3] = __float2bfloat16(fmaxf(0.f, (v0.w - mu) * rs * g0.w + e0.w));
  o1.h[0] = __float2bfloat16(fmaxf(0.f, (v1.x - mu) * rs * g1.x + e1.x));
  o1.h[1] = __float2bfloat16(fmaxf(0.f, (v1.y - mu) * rs * g1.y + e1.y));
  o1.h[2] = __float2bfloat16(fmaxf(0.f, (v1.z - mu) * rs * g1.z + e1.z));
  o1.h[3] = __float2bfloat16(fmaxf(0.f, (v1.w - mu) * rs * g1.w + e1.w));

  const int bq = row >> 8, t = row & 255;
  __hip_bfloat16* w = outpad + (size_t)(bq * TP_ + t + 1) * H_;
  *(ushort4*)(w + lane * 4)       = o0.u;
  *(ushort4*)(w + 256 + lane * 4) = o1.u;
}

// ---------------------------------------------------------------------------
// 7) linear head: one wave per row, dot(h2_row(bf16), Wl(f32)) + bl
// ---------------------------------------------------------------------------
__global__ __launch_bounds__(256) void linear_bf16_kernel(const __hip_bfloat16* __restrict__ Hpad,
                                                          const float* __restrict__ Wl,
                                                          const float* __restrict__ bl,
                                                          float* __restrict__ out) {
  const int wave = threadIdx.x >> 6;
  const int lane = threadIdx.x & 63;
  const int row  = blockIdx.x * 4 + wave;
  const int bq = row >> 8, t = row & 255;
  const __hip_bfloat16* r = Hpad + (size_t)(bq * TP_ + t + 1) * H_ + lane * 8;

  bf16x8 hv = *(const bf16x8*)r;
  const float4 w0 = *(const float4*)(Wl + lane * 8);
  const float4 w1 = *(const float4*)(Wl + lane * 8 + 4);

  const __hip_bfloat16* hh = (const __hip_bfloat16*)&hv;
  float s = __bfloat162float(hh[0]) * w0.x + __bfloat162float(hh[1]) * w0.y +
            __bfloat162float(hh[2]) * w0.z + __bfloat162float(hh[3]) * w0.w +
            __bfloat162float(hh[4]) * w1.x + __bfloat162float(hh[5]) * w1.y +
            __bfloat162float(hh[6]) * w1.z + __bfloat162float(hh[7]) * w1.w;
#pragma unroll
  for (int off = 32; off; off >>= 1) s += __shfl_xor(s, off);

  if (lane == 0) out[row] = s + bl[0];
}

// ---------------------------------------------------------------------------
extern "C" void kernel_launch(void* const* d_in, const int* in_sizes, int n_in,
                              void* d_out, int out_size, void* d_ws, size_t ws_size,
                              hipStream_t stream) {
  const float* x     = (const float*)d_in[0];
  const int*   dur   = (const int*)d_in[1];
  const float* W1    = (const float*)d_in[2];
  const float* b1    = (const float*)d_in[3];
  const float* g1    = (const float*)d_in[4];
  const float* beta1 = (const float*)d_in[5];
  const float* W2    = (const float*)d_in[6];
  const float* b2    = (const float*)d_in[7];
  const float* g2    = (const float*)d_in[8];
  const float* beta2 = (const float*)d_in[9];
  const float* Wl    = (const float*)d_in[10];
  const float* bl    = (const float*)d_in[11];

  float* out = (float*)d_out;
  float* res    = out;                              // [B, TOUT, C]
  float* loglen = out + (size_t)B_ * TOUT_ * C_;    // [B, T]

  char* ws = (char*)d_ws;
  int* csum = (int*)ws;                                             // 32 KB
  __hip_bfloat16* xpad = (__hip_bfloat16*)(ws + 32768);             // 8.45 MB
  __hip_bfloat16* hpad = xpad + (size_t)B_ * TP_ * C_;              // 8.45 MB
  __hip_bfloat16* Wt1  = hpad + (size_t)B_ * TP_ * C_;              // 1.57 MB
  __hip_bfloat16* Wt2  = Wt1 + (size_t)H_ * K_;                     // 1.57 MB
  float* tmp1 = (float*)(Wt2 + (size_t)H_ * K_);                    // 16.8 MB

  csum_kernel<<<B_, 256, 0, stream>>>(dur, csum);
  expand_kernel<<<B_ * TOUT_ / 8, 256, 0, stream>>>(x, csum, res);

  cvt_x_pad_kernel<<<B_ * TP_, 128, 0, stream>>>(x, xpad, hpad);
  cvt_wt_kernel<<<dim3(K_ / 32, H_ / 32, 2), 256, 0, stream>>>(W1, W2, Wt1, Wt2);

  conv_mfma_kernel<<<dim3(H_ / 128, B_ * T_ / 128), 256, 0, stream>>>(xpad, Wt1, b1, tmp1);
  ln_relu_pad_kernel<<<B_ * T_ / 4, 256, 0, stream>>>(tmp1, g1, beta1, hpad);
  conv_mfma_kernel<<<dim3(H_ / 128, B_ * T_ / 128), 256, 0, stream>>>(hpad, Wt2, b2, tmp1);
  ln_relu_pad_kernel<<<B_ * T_ / 4, 256, 0, stream>>>(tmp1, g2, beta2, xpad);  // reuse xpad for h2
  linear_bf16_kernel<<<B_ * T_ / 4, 256, 0, stream>>>(xpad, Wl, bl, loglen);
}

// Round 3
// 133.138 us; speedup vs baseline: 3.2209x; 1.0019x over previous
//
#include <hip/hip_runtime.h>
#include <hip/hip_bf16.h>

#define B_    32
#define T_    256
#define C_    512
#define H_    512
#define TOUT_ 2048
#define TP_   258        // padded time length (zero row at t=0 and t=257)
#define K_    1536       // 3 * 512
#define EPS_  1e-5f

typedef __attribute__((ext_vector_type(8))) short bf16x8;
typedef __attribute__((ext_vector_type(4))) float f32x4;

#define GLL16(g, l)                                                        \
  __builtin_amdgcn_global_load_lds(                                        \
      (const __attribute__((address_space(1))) void*)(g),                  \
      (__attribute__((address_space(3))) void*)(l), 16, 0, 0)

// ---------------------------------------------------------------------------
// 1) expand-by-durations gather with in-block cumsum scan
// ---------------------------------------------------------------------------
__global__ __launch_bounds__(256) void expand_kernel(const float* __restrict__ X,
                                                     const int* __restrict__ dur,
                                                     float* __restrict__ out) {
  __shared__ int sc[256];
  __shared__ int sidx[8];
  const int tid = threadIdx.x;
  const int b  = blockIdx.x >> 8;
  const int t0 = (blockIdx.x & 255) * 8;

  sc[tid] = dur[b * T_ + tid];
  __syncthreads();
#pragma unroll
  for (int off = 1; off < 256; off <<= 1) {
    int v = (tid >= off) ? sc[tid - off] : 0;
    __syncthreads();
    sc[tid] += v;
    __syncthreads();
  }
  const int total = sc[T_ - 1];
  if (tid < 8) {
    const int pos = t0 + tid;
    int l = 0, r = T_;
    while (l < r) { int m = (l + r) >> 1; if (sc[m] > pos) r = m; else l = m + 1; }
    sidx[tid] = (pos < total) ? min(l, T_ - 1) : -1;
  }
  __syncthreads();

  const int half = tid >> 7;
  const int c4   = tid & 127;
  const float4 z = make_float4(0.f, 0.f, 0.f, 0.f);
#pragma unroll
  for (int rr = half; rr < 8; rr += 2) {
    const int idx = sidx[rr];
    float4 v = z;
    if (idx >= 0)
      v = *(const float4*)(X + (size_t)(b * T_ + idx) * C_ + c4 * 4);
    *(float4*)(out + (size_t)(b * TOUT_ + t0 + rr) * C_ + c4 * 4) = v;
  }
}

// ---------------------------------------------------------------------------
// 2) convert x (f32) -> padded bf16 [32][258][512]; also zero pad rows of hpad
// ---------------------------------------------------------------------------
__global__ __launch_bounds__(128) void cvt_x_pad_kernel(const float* __restrict__ X,
                                                        __hip_bfloat16* __restrict__ xpad,
                                                        __hip_bfloat16* __restrict__ hpad) {
  const int row = blockIdx.x;           // 0 .. 32*258-1
  const int b = row / TP_;
  const int t = row - b * TP_;
  const int c = threadIdx.x * 4;
  __hip_bfloat16* dst = xpad + (size_t)row * C_ + c;
  if (t == 0 || t == TP_ - 1) {
    ushort4 zz = make_ushort4(0, 0, 0, 0);
    *(ushort4*)dst = zz;
    *(ushort4*)(hpad + (size_t)row * C_ + c) = zz;
    return;
  }
  const float4 v = *(const float4*)(X + (size_t)(b * T_ + t - 1) * C_ + c);
  union { __hip_bfloat16 h[4]; ushort4 u; } o;
  o.h[0] = __float2bfloat16(v.x);
  o.h[1] = __float2bfloat16(v.y);
  o.h[2] = __float2bfloat16(v.z);
  o.h[3] = __float2bfloat16(v.w);
  *(ushort4*)dst = o.u;
}

// ---------------------------------------------------------------------------
// 3) weight transpose+convert: W [1536][512] f32 -> Wt [512][1536] bf16
// ---------------------------------------------------------------------------
__global__ __launch_bounds__(256) void cvt_wt_kernel(const float* __restrict__ W1,
                                                     const float* __restrict__ W2,
                                                     __hip_bfloat16* __restrict__ Wt1,
                                                     __hip_bfloat16* __restrict__ Wt2) {
  __shared__ float tile[32][33];
  const float* W = blockIdx.z ? W2 : W1;
  __hip_bfloat16* Wt = blockIdx.z ? Wt2 : Wt1;
  const int k0 = blockIdx.x * 32;
  const int n0 = blockIdx.y * 32;
  const int tx = threadIdx.x & 31;
  const int ty = threadIdx.x >> 5;
#pragma unroll
  for (int i = 0; i < 4; ++i)
    tile[ty * 4 + i][tx] = W[(size_t)(k0 + ty * 4 + i) * H_ + n0 + tx];
  __syncthreads();
#pragma unroll
  for (int i = 0; i < 4; ++i)
    Wt[(size_t)(n0 + ty * 4 + i) * K_ + k0 + tx] =
        __float2bfloat16(tile[tx][ty * 4 + i]);
}

// ---------------------------------------------------------------------------
// 4) conv1d(k=3) as bf16 MFMA GEMM. M=8192, K=1536, N=512.
//    64(M)x128(N) tile, BK=32, 4 waves; wave = 64x32 (4x2 frags).
//    Grid = 4 x 128 = 512 blocks = 2 blocks/CU.
//    LDS per buf: A [4][64][8], B [4][128][8] bf16; GLL dests linear (tid*16B).
// ---------------------------------------------------------------------------
__global__ __launch_bounds__(256) void conv_mfma_kernel(
    const __hip_bfloat16* __restrict__ Apad,   // [32*258, 512]
    const __hip_bfloat16* __restrict__ Wt,     // [512, 1536]
    const float* __restrict__ bias,            // [512]
    float* __restrict__ Y) {                   // [8192, 512]
  __shared__ __hip_bfloat16 smA[2][2048];      // 8 KB
  __shared__ __hip_bfloat16 smB[2][4096];      // 16 KB

  const int tid  = threadIdx.x;
  const int lane = tid & 63;
  const int wid  = tid >> 6;
  const int m0 = blockIdx.y << 6;
  const int n0 = blockIdx.x << 7;
  const int b  = m0 >> 8;
  const int t0 = m0 & 255;
  const int wn = wid << 5;               // wave n-offset: 0,32,64,96

  // A staging: row ra = tid&63, k-slab ga = tid>>6 (one GLL16)
  const int ra = tid & 63;
  const int ga = tid >> 6;
  const __hip_bfloat16* arow = Apad + (size_t)(b * TP_ + t0 + ra) * C_;
  // B staging: row rb = tid&127, k-slabs gb and gb+2 (two GLL16)
  const int rb = tid & 127;
  const int gb = tid >> 7;
  const __hip_bfloat16* brow = Wt + (size_t)(n0 + rb) * K_;

  f32x4 acc[4][2] = {};

  auto stage = [&](int buf, int k0) {
    const int kw = k0 >> 9;              // 0..2 (BK=32 never straddles 512)
    const int c0 = k0 & 511;
    GLL16(arow + kw * C_ + c0 + (ga << 3), &smA[buf][tid << 3]);
    GLL16(brow + k0 + (gb << 3), &smB[buf][tid << 3]);
    GLL16(brow + k0 + ((gb + 2) << 3), &smB[buf][(tid << 3) + 2048]);
  };

  auto compute = [&](int buf) {
    const __hip_bfloat16* As = smA[buf];
    const __hip_bfloat16* Bs = smB[buf];
    const int g   = lane >> 4;
    const int r15 = lane & 15;
    bf16x8 aF[4], bF[2];
#pragma unroll
    for (int i = 0; i < 4; ++i)
      aF[i] = *(const bf16x8*)(As + (g << 9) + (((i << 4) + r15) << 3));
#pragma unroll
    for (int i = 0; i < 2; ++i)
      bF[i] = *(const bf16x8*)(Bs + (g << 10) + ((wn + (i << 4) + r15) << 3));
#pragma unroll
    for (int mi = 0; mi < 4; ++mi)
#pragma unroll
      for (int ni = 0; ni < 2; ++ni)
        acc[mi][ni] = __builtin_amdgcn_mfma_f32_16x16x32_bf16(
            aF[mi], bF[ni], acc[mi][ni], 0, 0, 0);
  };

  stage(0, 0);
  __syncthreads();
  int cur = 0;
  for (int k0 = 32; k0 < K_; k0 += 32) {
    stage(cur ^ 1, k0);
    compute(cur);
    __syncthreads();
    cur ^= 1;
  }
  compute(cur);

  // epilogue: C/D layout col = lane&15 (n), row = (lane>>4)*4 + reg (m)
  const int cn_base = n0 + wn + (lane & 15);
  const int rm_base = m0 + ((lane >> 4) << 2);
#pragma unroll
  for (int ni = 0; ni < 2; ++ni) {
    const int cn = cn_base + (ni << 4);
    const float bb = bias[cn];
#pragma unroll
    for (int mi = 0; mi < 4; ++mi) {
#pragma unroll
      for (int rq = 0; rq < 4; ++rq) {
        const int rm = rm_base + (mi << 4) + rq;
        Y[(size_t)rm * H_ + cn] = acc[mi][ni][rq] + bb;
      }
    }
  }
}

// ---------------------------------------------------------------------------
// 5) LayerNorm + ReLU, f32 in -> bf16 out written into padded layout
// ---------------------------------------------------------------------------
__global__ __launch_bounds__(256) void ln_relu_pad_kernel(const float* __restrict__ in,
                                                          const float* __restrict__ g,
                                                          const float* __restrict__ beta,
                                                          __hip_bfloat16* __restrict__ outpad) {
  const int wave = threadIdx.x >> 6;
  const int lane = threadIdx.x & 63;
  const int row  = blockIdx.x * 4 + wave;   // 0..8191
  const float* r = in + (size_t)row * H_;

  const float4 v0 = *(const float4*)(r + lane * 4);
  const float4 v1 = *(const float4*)(r + 256 + lane * 4);

  float s = v0.x + v0.y + v0.z + v0.w + v1.x + v1.y + v1.z + v1.w;
  float q = v0.x * v0.x + v0.y * v0.y + v0.z * v0.z + v0.w * v0.w +
            v1.x * v1.x + v1.y * v1.y + v1.z * v1.z + v1.w * v1.w;
#pragma unroll
  for (int off = 32; off; off >>= 1) {
    s += __shfl_xor(s, off);
    q += __shfl_xor(q, off);
  }
  const float mu  = s * (1.0f / 512.0f);
  const float var = q * (1.0f / 512.0f) - mu * mu;
  const float rs  = rsqrtf(var + EPS_);

  const float4 g0 = *(const float4*)(g + lane * 4);
  const float4 g1 = *(const float4*)(g + 256 + lane * 4);
  const float4 e0 = *(const float4*)(beta + lane * 4);
  const float4 e1 = *(const float4*)(beta + 256 + lane * 4);

  union { __hip_bfloat16 h[4]; ushort4 u; } o0, o1;
  o0.h[0] = __float2bfloat16(fmaxf(0.f, (v0.x - mu) * rs * g0.x + e0.x));
  o0.h[1] = __float2bfloat16(fmaxf(0.f, (v0.y - mu) * rs * g0.y + e0.y));
  o0.h[2] = __float2bfloat16(fmaxf(0.f, (v0.z - mu) * rs * g0.z + e0.z));
  o0.h[3] = __float2bfloat16(fmaxf(0.f, (v0.w - mu) * rs * g0.w + e0.w));
  o1.h[0] = __float2bfloat16(fmaxf(0.f, (v1.x - mu) * rs * g1.x + e1.x));
  o1.h[1] = __float2bfloat16(fmaxf(0.f, (v1.y - mu) * rs * g1.y + e1.y));
  o1.h[2] = __float2bfloat16(fmaxf(0.f, (v1.z - mu) * rs * g1.z + e1.z));
  o1.h[3] = __float2bfloat16(fmaxf(0.f, (v1.w - mu) * rs * g1.w + e1.w));

  const int bq = row >> 8, t = row & 255;
  __hip_bfloat16* w = outpad + (size_t)(bq * TP_ + t + 1) * H_;
  *(ushort4*)(w + lane * 4)       = o0.u;
  *(ushort4*)(w + 256 + lane * 4) = o1.u;
}

// ---------------------------------------------------------------------------
// 6) LayerNorm + ReLU + linear head fused: writes loglen[row] directly
// ---------------------------------------------------------------------------
__global__ __launch_bounds__(256) void ln_relu_linear_kernel(const float* __restrict__ in,
                                                             const float* __restrict__ g,
                                                             const float* __restrict__ beta,
                                                             const float* __restrict__ Wl,
                                                             const float* __restrict__ bl,
                                                             float* __restrict__ out) {
  const int wave = threadIdx.x >> 6;
  const int lane = threadIdx.x & 63;
  const int row  = blockIdx.x * 4 + wave;
  const float* r = in + (size_t)row * H_;

  const float4 v0 = *(const float4*)(r + lane * 4);
  const float4 v1 = *(const float4*)(r + 256 + lane * 4);

  float s = v0.x + v0.y + v0.z + v0.w + v1.x + v1.y + v1.z + v1.w;
  float q = v0.x * v0.x + v0.y * v0.y + v0.z * v0.z + v0.w * v0.w +
            v1.x * v1.x + v1.y * v1.y + v1.z * v1.z + v1.w * v1.w;
#pragma unroll
  for (int off = 32; off; off >>= 1) {
    s += __shfl_xor(s, off);
    q += __shfl_xor(q, off);
  }
  const float mu  = s * (1.0f / 512.0f);
  const float var = q * (1.0f / 512.0f) - mu * mu;
  const float rs  = rsqrtf(var + EPS_);

  const float4 g0 = *(const float4*)(g + lane * 4);
  const float4 g1 = *(const float4*)(g + 256 + lane * 4);
  const float4 e0 = *(const float4*)(beta + lane * 4);
  const float4 e1 = *(const float4*)(beta + 256 + lane * 4);
  const float4 w0 = *(const float4*)(Wl + lane * 4);
  const float4 w1 = *(const float4*)(Wl + 256 + lane * 4);

  float sd = 0.f;
  sd += fmaxf(0.f, (v0.x - mu) * rs * g0.x + e0.x) * w0.x;
  sd += fmaxf(0.f, (v0.y - mu) * rs * g0.y + e0.y) * w0.y;
  sd += fmaxf(0.f, (v0.z - mu) * rs * g0.z + e0.z) * w0.z;
  sd += fmaxf(0.f, (v0.w - mu) * rs * g0.w + e0.w) * w0.w;
  sd += fmaxf(0.f, (v1.x - mu) * rs * g1.x + e1.x) * w1.x;
  sd += fmaxf(0.f, (v1.y - mu) * rs * g1.y + e1.y) * w1.y;
  sd += fmaxf(0.f, (v1.z - mu) * rs * g1.z + e1.z) * w1.z;
  sd += fmaxf(0.f, (v1.w - mu) * rs * g1.w + e1.w) * w1.w;
#pragma unroll
  for (int off = 32; off; off >>= 1) sd += __shfl_xor(sd, off);

  if (lane == 0) out[row] = sd + bl[0];
}

// ---------------------------------------------------------------------------
extern "C" void kernel_launch(void* const* d_in, const int* in_sizes, int n_in,
                              void* d_out, int out_size, void* d_ws, size_t ws_size,
                              hipStream_t stream) {
  const float* x     = (const float*)d_in[0];
  const int*   dur   = (const int*)d_in[1];
  const float* W1    = (const float*)d_in[2];
  const float* b1    = (const float*)d_in[3];
  const float* g1    = (const float*)d_in[4];
  const float* beta1 = (const float*)d_in[5];
  const float* W2    = (const float*)d_in[6];
  const float* b2    = (const float*)d_in[7];
  const float* g2    = (const float*)d_in[8];
  const float* beta2 = (const float*)d_in[9];
  const float* Wl    = (const float*)d_in[10];
  const float* bl    = (const float*)d_in[11];

  float* out = (float*)d_out;
  float* res    = out;                              // [B, TOUT, C]
  float* loglen = out + (size_t)B_ * TOUT_ * C_;    // [B, T]

  char* ws = (char*)d_ws;
  __hip_bfloat16* xpad = (__hip_bfloat16*)ws;                       // 8.45 MB
  __hip_bfloat16* hpad = xpad + (size_t)B_ * TP_ * C_;              // 8.45 MB
  __hip_bfloat16* Wt1  = hpad + (size_t)B_ * TP_ * C_;              // 1.57 MB
  __hip_bfloat16* Wt2  = Wt1 + (size_t)H_ * K_;                     // 1.57 MB
  float* tmp1 = (float*)(Wt2 + (size_t)H_ * K_);                    // 16.8 MB

  expand_kernel<<<B_ * TOUT_ / 8, 256, 0, stream>>>(x, dur, res);

  cvt_x_pad_kernel<<<B_ * TP_, 128, 0, stream>>>(x, xpad, hpad);
  cvt_wt_kernel<<<dim3(K_ / 32, H_ / 32, 2), 256, 0, stream>>>(W1, W2, Wt1, Wt2);

  conv_mfma_kernel<<<dim3(H_ / 128, B_ * T_ / 64), 256, 0, stream>>>(xpad, Wt1, b1, tmp1);
  ln_relu_pad_kernel<<<B_ * T_ / 4, 256, 0, stream>>>(tmp1, g1, beta1, hpad);
  conv_mfma_kernel<<<dim3(H_ / 128, B_ * T_ / 64), 256, 0, stream>>>(hpad, Wt2, b2, tmp1);
  ln_relu_linear_kernel<<<B_ * T_ / 4, 256, 0, stream>>>(tmp1, g2, beta2, Wl, bl, loglen);
}

// Round 4
// 117.766 us; speedup vs baseline: 3.6413x; 1.1305x over previous
//
#include <hip/hip_runtime.h>
#include <hip/hip_bf16.h>

#define B_    32
#define T_    256
#define C_    512
#define H_    512
#define TOUT_ 2048
#define TP_   258        // padded time length (zero row at t=0 and t=257)
#define K_    1536       // 3 * 512
#define EPS_  1e-5f

typedef __attribute__((ext_vector_type(8))) short bf16x8;
typedef __attribute__((ext_vector_type(4))) float f32x4;

#define GLL16(g, l)                                                        \
  __builtin_amdgcn_global_load_lds(                                        \
      (const __attribute__((address_space(1))) void*)(g),                  \
      (__attribute__((address_space(3))) void*)(l), 16, 0, 0)

// ---------------------------------------------------------------------------
// helpers shared by heterogeneous kernels
// ---------------------------------------------------------------------------
__device__ __forceinline__ void wt_convert_block(const float* __restrict__ W,
                                                 __hip_bfloat16* __restrict__ Wt,
                                                 int k0, int n0, int tid,
                                                 float* tile /* [32][33] */) {
  const int tx = tid & 31;
  const int ty = tid >> 5;
#pragma unroll
  for (int i = 0; i < 4; ++i)
    tile[(ty * 4 + i) * 33 + tx] = W[(size_t)(k0 + ty * 4 + i) * H_ + n0 + tx];
  __syncthreads();
#pragma unroll
  for (int i = 0; i < 4; ++i)
    Wt[(size_t)(n0 + ty * 4 + i) * K_ + k0 + tx] =
        __float2bfloat16(tile[tx * 33 + ty * 4 + i]);
}

__device__ __forceinline__ void expand_block(const float* __restrict__ X,
                                             const int* __restrict__ dur,
                                             float* __restrict__ res,
                                             int e, int batch_base, int tid,
                                             int* sc /* >=292 ints */) {
  int* wsum = sc + 256;
  int* sidx = wsum + 4;
  const int b  = batch_base + (e >> 6);
  const int t0 = (e & 63) << 5;            // 32 output rows per block

  // wave-level inclusive scan of 256 durations (2 barriers total)
  int v = dur[b * T_ + tid];
#pragma unroll
  for (int off = 1; off < 64; off <<= 1) {
    int u = __shfl_up(v, off);
    if ((tid & 63) >= off) v += u;
  }
  if ((tid & 63) == 63) wsum[tid >> 6] = v;
  __syncthreads();
  int base = 0;
#pragma unroll
  for (int j = 0; j < 4; ++j)
    if (j < (tid >> 6)) base += wsum[j];
  sc[tid] = v + base;
  __syncthreads();
  const int total = sc[T_ - 1];
  if (tid < 32) {
    const int pos = t0 + tid;
    int l = 0, r = T_;
    while (l < r) { int m = (l + r) >> 1; if (sc[m] > pos) r = m; else l = m + 1; }
    sidx[tid] = (pos < total) ? min(l, T_ - 1) : -1;
  }
  __syncthreads();

  const int half = tid >> 7;
  const int c4   = tid & 127;
  const float4 z = make_float4(0.f, 0.f, 0.f, 0.f);
  for (int rr = half; rr < 32; rr += 2) {
    const int idx = sidx[rr];
    float4 vv = z;
    if (idx >= 0)
      vv = *(const float4*)(X + (size_t)(b * T_ + idx) * C_ + c4 * 4);
    *(float4*)(res + (size_t)(b * TOUT_ + t0 + rr) * C_ + c4 * 4) = vv;
  }
}

// ---------------------------------------------------------------------------
// 1) prep: cvt_x_pad (blocks 0..4127, 2 rows each) + cvt W1 (blocks 4128..4895)
// ---------------------------------------------------------------------------
__global__ __launch_bounds__(256) void prep_kernel(const float* __restrict__ X,
                                                   const float* __restrict__ W1,
                                                   __hip_bfloat16* __restrict__ xpad,
                                                   __hip_bfloat16* __restrict__ hpad,
                                                   __hip_bfloat16* __restrict__ Wt1) {
  __shared__ float tile[32 * 33];
  const int tid = threadIdx.x;
  if (blockIdx.x >= 4128) {
    const int id = blockIdx.x - 4128;       // 0..767
    wt_convert_block(W1, Wt1, (id % 48) * 32, (id / 48) * 32, tid, tile);
    return;
  }
  const int row = blockIdx.x * 2 + (tid >> 7);   // 0..8255
  const int b = row / TP_;
  const int t = row - b * TP_;
  const int c = (tid & 127) * 4;
  __hip_bfloat16* dst = xpad + (size_t)row * C_ + c;
  if (t == 0 || t == TP_ - 1) {
    ushort4 zz = make_ushort4(0, 0, 0, 0);
    *(ushort4*)dst = zz;
    *(ushort4*)(hpad + (size_t)row * C_ + c) = zz;
    return;
  }
  const float4 v = *(const float4*)(X + (size_t)(b * T_ + t - 1) * C_ + c);
  union { __hip_bfloat16 h[4]; ushort4 u; } o;
  o.h[0] = __float2bfloat16(v.x);
  o.h[1] = __float2bfloat16(v.y);
  o.h[2] = __float2bfloat16(v.z);
  o.h[3] = __float2bfloat16(v.w);
  *(ushort4*)dst = o.u;
}

// ---------------------------------------------------------------------------
// 2) heterogeneous: conv GEMM (blocks 0..511) || expand (512..1535)
//    || optional W2 transpose (1536..2303, first dispatch only)
//    conv: 64(M)x128(N) tile, BK=32, 4 waves, double-buffered GLL staging.
// ---------------------------------------------------------------------------
__global__ __launch_bounds__(256) void conv_expand_kernel(
    const __hip_bfloat16* __restrict__ Apad,   // [32*258, 512]
    const __hip_bfloat16* __restrict__ Wt,     // [512, 1536]
    const float* __restrict__ bias,            // [512]
    float* __restrict__ Y,                     // [8192, 512]
    const float* __restrict__ X,               // f32 input (for expand)
    const int* __restrict__ dur,
    float* __restrict__ res,
    const float* __restrict__ W2,              // may be null
    __hip_bfloat16* __restrict__ Wt2,          // may be null
    int batch_base) {
  __shared__ __hip_bfloat16 smA[2][2048];      // 8 KB
  __shared__ __hip_bfloat16 smB[2][4096];      // 16 KB

  const int tid = threadIdx.x;

  if (blockIdx.x >= 1536) {                    // W2 transpose ride-along
    const int id = blockIdx.x - 1536;          // 0..767
    wt_convert_block(W2, Wt2, (id % 48) * 32, (id / 48) * 32, tid, (float*)smA);
    return;
  }
  if (blockIdx.x >= 512) {                     // expand ride-along
    expand_block(X, dur, res, blockIdx.x - 512, batch_base, tid, (int*)smA);
    return;
  }

  // ---- conv GEMM path ----
  const int lane = tid & 63;
  const int wid  = tid >> 6;
  const int cid  = blockIdx.x;
  const int n0 = (cid & 3) << 7;
  const int m0 = (cid >> 2) << 6;
  const int b  = m0 >> 8;
  const int t0 = m0 & 255;
  const int wn = wid << 5;

  const int ra = tid & 63;
  const int ga = tid >> 6;
  const __hip_bfloat16* arow = Apad + (size_t)(b * TP_ + t0 + ra) * C_;
  const int rb = tid & 127;
  const int gb = tid >> 7;
  const __hip_bfloat16* brow = Wt + (size_t)(n0 + rb) * K_;

  f32x4 acc[4][2] = {};

  auto stage = [&](int buf, int k0) {
    const int kw = k0 >> 9;
    const int c0 = k0 & 511;
    GLL16(arow + kw * C_ + c0 + (ga << 3), &smA[buf][tid << 3]);
    GLL16(brow + k0 + (gb << 3), &smB[buf][tid << 3]);
    GLL16(brow + k0 + ((gb + 2) << 3), &smB[buf][(tid << 3) + 2048]);
  };

  auto compute = [&](int buf) {
    const __hip_bfloat16* As = smA[buf];
    const __hip_bfloat16* Bs = smB[buf];
    const int g   = lane >> 4;
    const int r15 = lane & 15;
    bf16x8 aF[4], bF[2];
#pragma unroll
    for (int i = 0; i < 4; ++i)
      aF[i] = *(const bf16x8*)(As + (g << 9) + (((i << 4) + r15) << 3));
#pragma unroll
    for (int i = 0; i < 2; ++i)
      bF[i] = *(const bf16x8*)(Bs + (g << 10) + ((wn + (i << 4) + r15) << 3));
#pragma unroll
    for (int mi = 0; mi < 4; ++mi)
#pragma unroll
      for (int ni = 0; ni < 2; ++ni)
        acc[mi][ni] = __builtin_amdgcn_mfma_f32_16x16x32_bf16(
            aF[mi], bF[ni], acc[mi][ni], 0, 0, 0);
  };

  stage(0, 0);
  __syncthreads();
  int cur = 0;
  for (int k0 = 32; k0 < K_; k0 += 32) {
    stage(cur ^ 1, k0);
    compute(cur);
    __syncthreads();
    cur ^= 1;
  }
  compute(cur);

  const int cn_base = n0 + wn + (lane & 15);
  const int rm_base = m0 + ((lane >> 4) << 2);
#pragma unroll
  for (int ni = 0; ni < 2; ++ni) {
    const int cn = cn_base + (ni << 4);
    const float bb = bias[cn];
#pragma unroll
    for (int mi = 0; mi < 4; ++mi) {
#pragma unroll
      for (int rq = 0; rq < 4; ++rq) {
        const int rm = rm_base + (mi << 4) + rq;
        Y[(size_t)rm * H_ + cn] = acc[mi][ni][rq] + bb;
      }
    }
  }
}

// ---------------------------------------------------------------------------
// 3) LayerNorm + ReLU, f32 in -> bf16 out written into padded layout
// ---------------------------------------------------------------------------
__global__ __launch_bounds__(256) void ln_relu_pad_kernel(const float* __restrict__ in,
                                                          const float* __restrict__ g,
                                                          const float* __restrict__ beta,
                                                          __hip_bfloat16* __restrict__ outpad) {
  const int wave = threadIdx.x >> 6;
  const int lane = threadIdx.x & 63;
  const int row  = blockIdx.x * 4 + wave;   // 0..8191
  const float* r = in + (size_t)row * H_;

  const float4 v0 = *(const float4*)(r + lane * 4);
  const float4 v1 = *(const float4*)(r + 256 + lane * 4);

  float s = v0.x + v0.y + v0.z + v0.w + v1.x + v1.y + v1.z + v1.w;
  float q = v0.x * v0.x + v0.y * v0.y + v0.z * v0.z + v0.w * v0.w +
            v1.x * v1.x + v1.y * v1.y + v1.z * v1.z + v1.w * v1.w;
#pragma unroll
  for (int off = 32; off; off >>= 1) {
    s += __shfl_xor(s, off);
    q += __shfl_xor(q, off);
  }
  const float mu  = s * (1.0f / 512.0f);
  const float var = q * (1.0f / 512.0f) - mu * mu;
  const float rs  = rsqrtf(var + EPS_);

  const float4 g0 = *(const float4*)(g + lane * 4);
  const float4 g1 = *(const float4*)(g + 256 + lane * 4);
  const float4 e0 = *(const float4*)(beta + lane * 4);
  const float4 e1 = *(const float4*)(beta + 256 + lane * 4);

  union { __hip_bfloat16 h[4]; ushort4 u; } o0, o1;
  o0.h[0] = __float2bfloat16(fmaxf(0.f, (v0.x - mu) * rs * g0.x + e0.x));
  o0.h[1] = __float2bfloat16(fmaxf(0.f, (v0.y - mu) * rs * g0.y + e0.y));
  o0.h[2] = __float2bfloat16(fmaxf(0.f, (v0.z - mu) * rs * g0.z + e0.z));
  o0.h[3] = __float2bfloat16(fmaxf(0.f, (v0.w - mu) * rs * g0.w + e0.w));
  o1.h[0] = __float2bfloat16(fmaxf(0.f, (v1.x - mu) * rs * g1.x + e1.x));
  o1.h[1] = __float2bfloat16(fmaxf(0.f, (v1.y - mu) * rs * g1.y + e1.y));
  o1.h[2] = __float2bfloat16(fmaxf(0.f, (v1.z - mu) * rs * g1.z + e1.z));
  o1.h[3] = __float2bfloat16(fmaxf(0.f, (v1.w - mu) * rs * g1.w + e1.w));

  const int bq = row >> 8, t = row & 255;
  __hip_bfloat16* w = outpad + (size_t)(bq * TP_ + t + 1) * H_;
  *(ushort4*)(w + lane * 4)       = o0.u;
  *(ushort4*)(w + 256 + lane * 4) = o1.u;
}

// ---------------------------------------------------------------------------
// 4) LayerNorm + ReLU + linear head fused
// ---------------------------------------------------------------------------
__global__ __launch_bounds__(256) void ln_relu_linear_kernel(const float* __restrict__ in,
                                                             const float* __restrict__ g,
                                                             const float* __restrict__ beta,
                                                             const float* __restrict__ Wl,
                                                             const float* __restrict__ bl,
                                                             float* __restrict__ out) {
  const int wave = threadIdx.x >> 6;
  const int lane = threadIdx.x & 63;
  const int row  = blockIdx.x * 4 + wave;
  const float* r = in + (size_t)row * H_;

  const float4 v0 = *(const float4*)(r + lane * 4);
  const float4 v1 = *(const float4*)(r + 256 + lane * 4);

  float s = v0.x + v0.y + v0.z + v0.w + v1.x + v1.y + v1.z + v1.w;
  float q = v0.x * v0.x + v0.y * v0.y + v0.z * v0.z + v0.w * v0.w +
            v1.x * v1.x + v1.y * v1.y + v1.z * v1.z + v1.w * v1.w;
#pragma unroll
  for (int off = 32; off; off >>= 1) {
    s += __shfl_xor(s, off);
    q += __shfl_xor(q, off);
  }
  const float mu  = s * (1.0f / 512.0f);
  const float var = q * (1.0f / 512.0f) - mu * mu;
  const float rs  = rsqrtf(var + EPS_);

  const float4 g0 = *(const float4*)(g + lane * 4);
  const float4 g1 = *(const float4*)(g + 256 + lane * 4);
  const float4 e0 = *(const float4*)(beta + lane * 4);
  const float4 e1 = *(const float4*)(beta + 256 + lane * 4);
  const float4 w0 = *(const float4*)(Wl + lane * 4);
  const float4 w1 = *(const float4*)(Wl + 256 + lane * 4);

  float sd = 0.f;
  sd += fmaxf(0.f, (v0.x - mu) * rs * g0.x + e0.x) * w0.x;
  sd += fmaxf(0.f, (v0.y - mu) * rs * g0.y + e0.y) * w0.y;
  sd += fmaxf(0.f, (v0.z - mu) * rs * g0.z + e0.z) * w0.z;
  sd += fmaxf(0.f, (v0.w - mu) * rs * g0.w + e0.w) * w0.w;
  sd += fmaxf(0.f, (v1.x - mu) * rs * g1.x + e1.x) * w1.x;
  sd += fmaxf(0.f, (v1.y - mu) * rs * g1.y + e1.y) * w1.y;
  sd += fmaxf(0.f, (v1.z - mu) * rs * g1.z + e1.z) * w1.z;
  sd += fmaxf(0.f, (v1.w - mu) * rs * g1.w + e1.w) * w1.w;
#pragma unroll
  for (int off = 32; off; off >>= 1) sd += __shfl_xor(sd, off);

  if (lane == 0) out[row] = sd + bl[0];
}

// ---------------------------------------------------------------------------
extern "C" void kernel_launch(void* const* d_in, const int* in_sizes, int n_in,
                              void* d_out, int out_size, void* d_ws, size_t ws_size,
                              hipStream_t stream) {
  const float* x     = (const float*)d_in[0];
  const int*   dur   = (const int*)d_in[1];
  const float* W1    = (const float*)d_in[2];
  const float* b1    = (const float*)d_in[3];
  const float* g1    = (const float*)d_in[4];
  const float* beta1 = (const float*)d_in[5];
  const float* W2    = (const float*)d_in[6];
  const float* b2    = (const float*)d_in[7];
  const float* g2    = (const float*)d_in[8];
  const float* beta2 = (const float*)d_in[9];
  const float* Wl    = (const float*)d_in[10];
  const float* bl    = (const float*)d_in[11];

  float* out = (float*)d_out;
  float* res    = out;                              // [B, TOUT, C]
  float* loglen = out + (size_t)B_ * TOUT_ * C_;    // [B, T]

  char* ws = (char*)d_ws;
  __hip_bfloat16* xpad = (__hip_bfloat16*)ws;                       // 8.45 MB
  __hip_bfloat16* hpad = xpad + (size_t)B_ * TP_ * C_;              // 8.45 MB
  __hip_bfloat16* Wt1  = hpad + (size_t)B_ * TP_ * C_;              // 1.57 MB
  __hip_bfloat16* Wt2  = Wt1 + (size_t)H_ * K_;                     // 1.57 MB
  float* tmp1 = (float*)(Wt2 + (size_t)H_ * K_);                    // 16.8 MB

  prep_kernel<<<4896, 256, 0, stream>>>(x, W1, xpad, hpad, Wt1);

  // conv1 || expand batches 0..15 || W2 transpose
  conv_expand_kernel<<<2304, 256, 0, stream>>>(xpad, Wt1, b1, tmp1,
                                               x, dur, res, W2, Wt2, 0);
  ln_relu_pad_kernel<<<B_ * T_ / 4, 256, 0, stream>>>(tmp1, g1, beta1, hpad);

  // conv2 || expand batches 16..31
  conv_expand_kernel<<<1536, 256, 0, stream>>>(hpad, Wt2, b2, tmp1,
                                               x, dur, res, nullptr, nullptr, 16);
  ln_relu_linear_kernel<<<B_ * T_ / 4, 256, 0, stream>>>(tmp1, g2, beta2, Wl, bl, loglen);
}

// Round 5
// 117.428 us; speedup vs baseline: 3.6518x; 1.0029x over previous
//
#include <hip/hip_runtime.h>
#include <hip/hip_bf16.h>

#define B_    32
#define T_    256
#define C_    512
#define H_    512
#define TOUT_ 2048
#define TP_   258        // padded time length (zero row at t=0 and t=257)
#define K_    1536       // 3 * 512
#define EPS_  1e-5f

typedef __attribute__((ext_vector_type(8))) short bf16x8;
typedef __attribute__((ext_vector_type(4))) float f32x4;

#define GLL16(g, l)                                                        \
  __builtin_amdgcn_global_load_lds(                                        \
      (const __attribute__((address_space(1))) void*)(g),                  \
      (__attribute__((address_space(3))) void*)(l), 16, 0, 0)

// ---------------------------------------------------------------------------
// helpers shared by heterogeneous kernels
// ---------------------------------------------------------------------------
__device__ __forceinline__ void wt_convert_block(const float* __restrict__ W,
                                                 __hip_bfloat16* __restrict__ Wt,
                                                 int k0, int n0, int tid,
                                                 float* tile /* [32][33] */) {
  const int tx = tid & 31;
  const int ty = tid >> 5;
#pragma unroll
  for (int i = 0; i < 4; ++i)
    tile[(ty * 4 + i) * 33 + tx] = W[(size_t)(k0 + ty * 4 + i) * H_ + n0 + tx];
  __syncthreads();
#pragma unroll
  for (int i = 0; i < 4; ++i)
    Wt[(size_t)(n0 + ty * 4 + i) * K_ + k0 + tx] =
        __float2bfloat16(tile[tx * 33 + ty * 4 + i]);
}

// inclusive scan of one batch's 256 durations -> csum (2 barriers)
__device__ __forceinline__ void csum_block(const int* __restrict__ dur,
                                           int* __restrict__ csum,
                                           int b, int tid, int* wsum /*>=4 ints*/) {
  int v = dur[b * T_ + tid];
#pragma unroll
  for (int off = 1; off < 64; off <<= 1) {
    int u = __shfl_up(v, off);
    if ((tid & 63) >= off) v += u;
  }
  if ((tid & 63) == 63) wsum[tid >> 6] = v;
  __syncthreads();
  int base = 0;
#pragma unroll
  for (int j = 0; j < 4; ++j)
    if (j < (tid >> 6)) base += wsum[j];
  csum[b * T_ + tid] = v + base;
}

// copy block: 16 source rows, one row per wave-iteration; read row once,
// write its d consecutive output rows (coalesced float4 stores)
__device__ __forceinline__ void expand_copy_block(const float* __restrict__ X,
                                                  const int* __restrict__ csum,
                                                  float* __restrict__ res,
                                                  int u, int tid) {
  const int wave = tid >> 6, lane = tid & 63;
#pragma unroll
  for (int k = 0; k < 4; ++k) {
    const int sr = u * 16 + wave * 4 + k;    // 0..8191
    const int b = sr >> 8, t = sr & 255;
    const int* cb = csum + b * T_;
    const int c0 = t ? cb[t - 1] : 0;
    const int d  = cb[t] - c0;
    if (d == 0) continue;
    const float* src = X + (size_t)sr * C_;
    const float4 v0 = *(const float4*)(src + lane * 4);
    const float4 v1 = *(const float4*)(src + 256 + lane * 4);
    float* dst = res + ((size_t)b * TOUT_ + c0) * C_;
    for (int j = 0; j < d; ++j) {
      *(float4*)(dst + (size_t)j * C_ + lane * 4)       = v0;
      *(float4*)(dst + (size_t)j * C_ + 256 + lane * 4) = v1;
    }
  }
}

// zero block: 32 output rows of one batch, zero those >= total
__device__ __forceinline__ void expand_zero_block(const int* __restrict__ csum,
                                                  float* __restrict__ res,
                                                  int z, int tid) {
  const int b  = z >> 6;
  const int t0 = (z & 63) << 5;
  const int total = csum[b * T_ + 255];
  const float4 z4 = make_float4(0.f, 0.f, 0.f, 0.f);
  const int half = tid >> 7, c4 = tid & 127;
#pragma unroll
  for (int rr = half; rr < 32; rr += 2) {
    const int r = t0 + rr;
    if (r >= total)
      *(float4*)(res + ((size_t)b * TOUT_ + r) * C_ + c4 * 4) = z4;
  }
}

// ---------------------------------------------------------------------------
// 1) prep: cvt_x_pad (0..4127) + cvt W1 (4128..4895) + csum (4896..4927)
// ---------------------------------------------------------------------------
__global__ __launch_bounds__(256) void prep_kernel(const float* __restrict__ X,
                                                   const float* __restrict__ W1,
                                                   const int* __restrict__ dur,
                                                   __hip_bfloat16* __restrict__ xpad,
                                                   __hip_bfloat16* __restrict__ hpad,
                                                   __hip_bfloat16* __restrict__ Wt1,
                                                   int* __restrict__ csum) {
  __shared__ float tile[32 * 33];
  const int tid = threadIdx.x;
  if (blockIdx.x >= 4896) {
    csum_block(dur, csum, blockIdx.x - 4896, tid, (int*)tile);
    return;
  }
  if (blockIdx.x >= 4128) {
    const int id = blockIdx.x - 4128;       // 0..767
    wt_convert_block(W1, Wt1, (id % 48) * 32, (id / 48) * 32, tid, tile);
    return;
  }
  const int row = blockIdx.x * 2 + (tid >> 7);   // 0..8255
  const int b = row / TP_;
  const int t = row - b * TP_;
  const int c = (tid & 127) * 4;
  __hip_bfloat16* dst = xpad + (size_t)row * C_ + c;
  if (t == 0 || t == TP_ - 1) {
    ushort4 zz = make_ushort4(0, 0, 0, 0);
    *(ushort4*)dst = zz;
    *(ushort4*)(hpad + (size_t)row * C_ + c) = zz;
    return;
  }
  const float4 v = *(const float4*)(X + (size_t)(b * T_ + t - 1) * C_ + c);
  union { __hip_bfloat16 h[4]; ushort4 u; } o;
  o.h[0] = __float2bfloat16(v.x);
  o.h[1] = __float2bfloat16(v.y);
  o.h[2] = __float2bfloat16(v.z);
  o.h[3] = __float2bfloat16(v.w);
  *(ushort4*)dst = o.u;
}

// ---------------------------------------------------------------------------
// 2) heterogeneous: conv GEMM (0..511) || expand units (512..1791)
//    || optional W2 transpose (1792..2559, first dispatch only)
//    expand unit u (global, via ex_base): u<512 copy block, else zero block.
// ---------------------------------------------------------------------------
__global__ __launch_bounds__(256) void conv_expand_kernel(
    const __hip_bfloat16* __restrict__ Apad,   // [32*258, 512]
    const __hip_bfloat16* __restrict__ Wt,     // [512, 1536]
    const float* __restrict__ bias,            // [512]
    float* __restrict__ Y,                     // [8192, 512]
    const float* __restrict__ X,               // f32 input (for expand)
    const int* __restrict__ csum,
    float* __restrict__ res,
    const float* __restrict__ W2,              // may be null
    __hip_bfloat16* __restrict__ Wt2,          // may be null
    int ex_base) {
  __shared__ __hip_bfloat16 smA[2][2048];      // 8 KB
  __shared__ __hip_bfloat16 smB[2][4096];      // 16 KB

  const int tid = threadIdx.x;

  if (blockIdx.x >= 1792) {                    // W2 transpose ride-along
    const int id = blockIdx.x - 1792;          // 0..767
    wt_convert_block(W2, Wt2, (id % 48) * 32, (id / 48) * 32, tid, (float*)smA);
    return;
  }
  if (blockIdx.x >= 512) {                     // expand ride-along
    const int u = ex_base + (blockIdx.x - 512);
    if (u < 512) expand_copy_block(X, csum, res, u, tid);
    else         expand_zero_block(csum, res, u - 512, tid);
    return;
  }

  // ---- conv GEMM path ----
  const int lane = tid & 63;
  const int wid  = tid >> 6;
  const int cid  = blockIdx.x;
  const int n0 = (cid & 3) << 7;
  const int m0 = (cid >> 2) << 6;
  const int b  = m0 >> 8;
  const int t0 = m0 & 255;
  const int wn = wid << 5;

  const int ra = tid & 63;
  const int ga = tid >> 6;
  const __hip_bfloat16* arow = Apad + (size_t)(b * TP_ + t0 + ra) * C_;
  const int rb = tid & 127;
  const int gb = tid >> 7;
  const __hip_bfloat16* brow = Wt + (size_t)(n0 + rb) * K_;

  f32x4 acc[4][2] = {};

  auto stage = [&](int buf, int k0) {
    const int kw = k0 >> 9;
    const int c0 = k0 & 511;
    GLL16(arow + kw * C_ + c0 + (ga << 3), &smA[buf][tid << 3]);
    GLL16(brow + k0 + (gb << 3), &smB[buf][tid << 3]);
    GLL16(brow + k0 + ((gb + 2) << 3), &smB[buf][(tid << 3) + 2048]);
  };

  auto compute = [&](int buf) {
    const __hip_bfloat16* As = smA[buf];
    const __hip_bfloat16* Bs = smB[buf];
    const int g   = lane >> 4;
    const int r15 = lane & 15;
    bf16x8 aF[4], bF[2];
#pragma unroll
    for (int i = 0; i < 4; ++i)
      aF[i] = *(const bf16x8*)(As + (g << 9) + (((i << 4) + r15) << 3));
#pragma unroll
    for (int i = 0; i < 2; ++i)
      bF[i] = *(const bf16x8*)(Bs + (g << 10) + ((wn + (i << 4) + r15) << 3));
#pragma unroll
    for (int mi = 0; mi < 4; ++mi)
#pragma unroll
      for (int ni = 0; ni < 2; ++ni)
        acc[mi][ni] = __builtin_amdgcn_mfma_f32_16x16x32_bf16(
            aF[mi], bF[ni], acc[mi][ni], 0, 0, 0);
  };

  stage(0, 0);
  __syncthreads();
  int cur = 0;
  for (int k0 = 32; k0 < K_; k0 += 32) {
    stage(cur ^ 1, k0);
    compute(cur);
    __syncthreads();
    cur ^= 1;
  }
  compute(cur);

  const int cn_base = n0 + wn + (lane & 15);
  const int rm_base = m0 + ((lane >> 4) << 2);
#pragma unroll
  for (int ni = 0; ni < 2; ++ni) {
    const int cn = cn_base + (ni << 4);
    const float bb = bias[cn];
#pragma unroll
    for (int mi = 0; mi < 4; ++mi) {
#pragma unroll
      for (int rq = 0; rq < 4; ++rq) {
        const int rm = rm_base + (mi << 4) + rq;
        Y[(size_t)rm * H_ + cn] = acc[mi][ni][rq] + bb;
      }
    }
  }
}

// ---------------------------------------------------------------------------
// 3) LayerNorm + ReLU, f32 in -> bf16 out written into padded layout
// ---------------------------------------------------------------------------
__global__ __launch_bounds__(256) void ln_relu_pad_kernel(const float* __restrict__ in,
                                                          const float* __restrict__ g,
                                                          const float* __restrict__ beta,
                                                          __hip_bfloat16* __restrict__ outpad) {
  const int wave = threadIdx.x >> 6;
  const int lane = threadIdx.x & 63;
  const int row  = blockIdx.x * 4 + wave;   // 0..8191
  const float* r = in + (size_t)row * H_;

  const float4 v0 = *(const float4*)(r + lane * 4);
  const float4 v1 = *(const float4*)(r + 256 + lane * 4);

  float s = v0.x + v0.y + v0.z + v0.w + v1.x + v1.y + v1.z + v1.w;
  float q = v0.x * v0.x + v0.y * v0.y + v0.z * v0.z + v0.w * v0.w +
            v1.x * v1.x + v1.y * v1.y + v1.z * v1.z + v1.w * v1.w;
#pragma unroll
  for (int off = 32; off; off >>= 1) {
    s += __shfl_xor(s, off);
    q += __shfl_xor(q, off);
  }
  const float mu  = s * (1.0f / 512.0f);
  const float var = q * (1.0f / 512.0f) - mu * mu;
  const float rs  = rsqrtf(var + EPS_);

  const float4 g0 = *(const float4*)(g + lane * 4);
  const float4 g1 = *(const float4*)(g + 256 + lane * 4);
  const float4 e0 = *(const float4*)(beta + lane * 4);
  const float4 e1 = *(const float4*)(beta + 256 + lane * 4);

  union { __hip_bfloat16 h[4]; ushort4 u; } o0, o1;
  o0.h[0] = __float2bfloat16(fmaxf(0.f, (v0.x - mu) * rs * g0.x + e0.x));
  o0.h[1] = __float2bfloat16(fmaxf(0.f, (v0.y - mu) * rs * g0.y + e0.y));
  o0.h[2] = __float2bfloat16(fmaxf(0.f, (v0.z - mu) * rs * g0.z + e0.z));
  o0.h[3] = __float2bfloat16(fmaxf(0.f, (v0.w - mu) * rs * g0.w + e0.w));
  o1.h[0] = __float2bfloat16(fmaxf(0.f, (v1.x - mu) * rs * g1.x + e1.x));
  o1.h[1] = __float2bfloat16(fmaxf(0.f, (v1.y - mu) * rs * g1.y + e1.y));
  o1.h[2] = __float2bfloat16(fmaxf(0.f, (v1.z - mu) * rs * g1.z + e1.z));
  o1.h[3] = __float2bfloat16(fmaxf(0.f, (v1.w - mu) * rs * g1.w + e1.w));

  const int bq = row >> 8, t = row & 255;
  __hip_bfloat16* w = outpad + (size_t)(bq * TP_ + t + 1) * H_;
  *(ushort4*)(w + lane * 4)       = o0.u;
  *(ushort4*)(w + 256 + lane * 4) = o1.u;
}

// ---------------------------------------------------------------------------
// 4) LayerNorm + ReLU + linear head fused
// ---------------------------------------------------------------------------
__global__ __launch_bounds__(256) void ln_relu_linear_kernel(const float* __restrict__ in,
                                                             const float* __restrict__ g,
                                                             const float* __restrict__ beta,
                                                             const float* __restrict__ Wl,
                                                             const float* __restrict__ bl,
                                                             float* __restrict__ out) {
  const int wave = threadIdx.x >> 6;
  const int lane = threadIdx.x & 63;
  const int row  = blockIdx.x * 4 + wave;
  const float* r = in + (size_t)row * H_;

  const float4 v0 = *(const float4*)(r + lane * 4);
  const float4 v1 = *(const float4*)(r + 256 + lane * 4);

  float s = v0.x + v0.y + v0.z + v0.w + v1.x + v1.y + v1.z + v1.w;
  float q = v0.x * v0.x + v0.y * v0.y + v0.z * v0.z + v0.w * v0.w +
            v1.x * v1.x + v1.y * v1.y + v1.z * v1.z + v1.w * v1.w;
#pragma unroll
  for (int off = 32; off; off >>= 1) {
    s += __shfl_xor(s, off);
    q += __shfl_xor(q, off);
  }
  const float mu  = s * (1.0f / 512.0f);
  const float var = q * (1.0f / 512.0f) - mu * mu;
  const float rs  = rsqrtf(var + EPS_);

  const float4 g0 = *(const float4*)(g + lane * 4);
  const float4 g1 = *(const float4*)(g + 256 + lane * 4);
  const float4 e0 = *(const float4*)(beta + lane * 4);
  const float4 e1 = *(const float4*)(beta + 256 + lane * 4);
  const float4 w0 = *(const float4*)(Wl + lane * 4);
  const float4 w1 = *(const float4*)(Wl + 256 + lane * 4);

  float sd = 0.f;
  sd += fmaxf(0.f, (v0.x - mu) * rs * g0.x + e0.x) * w0.x;
  sd += fmaxf(0.f, (v0.y - mu) * rs * g0.y + e0.y) * w0.y;
  sd += fmaxf(0.f, (v0.z - mu) * rs * g0.z + e0.z) * w0.z;
  sd += fmaxf(0.f, (v0.w - mu) * rs * g0.w + e0.w) * w0.w;
  sd += fmaxf(0.f, (v1.x - mu) * rs * g1.x + e1.x) * w1.x;
  sd += fmaxf(0.f, (v1.y - mu) * rs * g1.y + e1.y) * w1.y;
  sd += fmaxf(0.f, (v1.z - mu) * rs * g1.z + e1.z) * w1.z;
  sd += fmaxf(0.f, (v1.w - mu) * rs * g1.w + e1.w) * w1.w;
#pragma unroll
  for (int off = 32; off; off >>= 1) sd += __shfl_xor(sd, off);

  if (lane == 0) out[row] = sd + bl[0];
}

// ---------------------------------------------------------------------------
extern "C" void kernel_launch(void* const* d_in, const int* in_sizes, int n_in,
                              void* d_out, int out_size, void* d_ws, size_t ws_size,
                              hipStream_t stream) {
  const float* x     = (const float*)d_in[0];
  const int*   dur   = (const int*)d_in[1];
  const float* W1    = (const float*)d_in[2];
  const float* b1    = (const float*)d_in[3];
  const float* g1    = (const float*)d_in[4];
  const float* beta1 = (const float*)d_in[5];
  const float* W2    = (const float*)d_in[6];
  const float* b2    = (const float*)d_in[7];
  const float* g2    = (const float*)d_in[8];
  const float* beta2 = (const float*)d_in[9];
  const float* Wl    = (const float*)d_in[10];
  const float* bl    = (const float*)d_in[11];

  float* out = (float*)d_out;
  float* res    = out;                              // [B, TOUT, C]
  float* loglen = out + (size_t)B_ * TOUT_ * C_;    // [B, T]

  char* ws = (char*)d_ws;
  __hip_bfloat16* xpad = (__hip_bfloat16*)ws;                       // 8.45 MB
  __hip_bfloat16* hpad = xpad + (size_t)B_ * TP_ * C_;              // 8.45 MB
  __hip_bfloat16* Wt1  = hpad + (size_t)B_ * TP_ * C_;              // 1.57 MB
  __hip_bfloat16* Wt2  = Wt1 + (size_t)H_ * K_;                     // 1.57 MB
  float* tmp1 = (float*)(Wt2 + (size_t)H_ * K_);                    // 16.8 MB
  int*   csum = (int*)(tmp1 + (size_t)B_ * T_ * H_);                // 32 KB

  prep_kernel<<<4928, 256, 0, stream>>>(x, W1, dur, xpad, hpad, Wt1, csum);

  // conv1 || expand units 0..1279 (all copies + zeros 0..767) || W2 transpose
  conv_expand_kernel<<<2560, 256, 0, stream>>>(xpad, Wt1, b1, tmp1,
                                               x, csum, res, W2, Wt2, 0);
  ln_relu_pad_kernel<<<B_ * T_ / 4, 256, 0, stream>>>(tmp1, g1, beta1, hpad);

  // conv2 || expand units 1280..2559 (zeros 768..2047)
  conv_expand_kernel<<<1792, 256, 0, stream>>>(hpad, Wt2, b2, tmp1,
                                               x, csum, res, nullptr, nullptr, 1280);
  ln_relu_linear_kernel<<<B_ * T_ / 4, 256, 0, stream>>>(tmp1, g2, beta2, Wl, bl, loglen);
}

// Round 6
// 116.805 us; speedup vs baseline: 3.6713x; 1.0053x over previous
//
#include <hip/hip_runtime.h>
#include <hip/hip_bf16.h>

#define B_    32
#define T_    256
#define C_    512
#define H_    512
#define TOUT_ 2048
#define TP_   258        // padded time length (zero row at t=0 and t=257)
#define K_    1536       // 3 * 512
#define EPS_  1e-5f

typedef __attribute__((ext_vector_type(8))) short bf16x8;
typedef __attribute__((ext_vector_type(4))) float f32x4;

#define GLL16(g, l)                                                        \
  __builtin_amdgcn_global_load_lds(                                        \
      (const __attribute__((address_space(1))) void*)(g),                  \
      (__attribute__((address_space(3))) void*)(l), 16, 0, 0)

// ---------------------------------------------------------------------------
// helpers shared by heterogeneous kernels
// ---------------------------------------------------------------------------
__device__ __forceinline__ void wt_convert_block(const float* __restrict__ W,
                                                 __hip_bfloat16* __restrict__ Wt,
                                                 int k0, int n0, int tid,
                                                 float* tile /* [32][33] */) {
  const int tx = tid & 31;
  const int ty = tid >> 5;
#pragma unroll
  for (int i = 0; i < 4; ++i)
    tile[(ty * 4 + i) * 33 + tx] = W[(size_t)(k0 + ty * 4 + i) * H_ + n0 + tx];
  __syncthreads();
#pragma unroll
  for (int i = 0; i < 4; ++i)
    Wt[(size_t)(n0 + ty * 4 + i) * K_ + k0 + tx] =
        __float2bfloat16(tile[tx * 33 + ty * 4 + i]);
}

// inclusive scan of one batch's 256 durations -> csum (2 barriers)
__device__ __forceinline__ void csum_block(const int* __restrict__ dur,
                                           int* __restrict__ csum,
                                           int b, int tid, int* wsum /*>=4 ints*/) {
  int v = dur[b * T_ + tid];
#pragma unroll
  for (int off = 1; off < 64; off <<= 1) {
    int u = __shfl_up(v, off);
    if ((tid & 63) >= off) v += u;
  }
  if ((tid & 63) == 63) wsum[tid >> 6] = v;
  __syncthreads();
  int base = 0;
#pragma unroll
  for (int j = 0; j < 4; ++j)
    if (j < (tid >> 6)) base += wsum[j];
  csum[b * T_ + tid] = v + base;
}

// copy block: 16 source rows, one row per wave-iteration; read row once,
// write its d consecutive output rows (coalesced float4 stores)
__device__ __forceinline__ void expand_copy_block(const float* __restrict__ X,
                                                  const int* __restrict__ csum,
                                                  float* __restrict__ res,
                                                  int u, int tid) {
  const int wave = tid >> 6, lane = tid & 63;
#pragma unroll
  for (int k = 0; k < 4; ++k) {
    const int sr = u * 16 + wave * 4 + k;    // 0..8191
    const int b = sr >> 8, t = sr & 255;
    const int* cb = csum + b * T_;
    const int c0 = t ? cb[t - 1] : 0;
    const int d  = cb[t] - c0;
    if (d == 0) continue;
    const float* src = X + (size_t)sr * C_;
    const float4 v0 = *(const float4*)(src + lane * 4);
    const float4 v1 = *(const float4*)(src + 256 + lane * 4);
    float* dst = res + ((size_t)b * TOUT_ + c0) * C_;
    for (int j = 0; j < d; ++j) {
      *(float4*)(dst + (size_t)j * C_ + lane * 4)       = v0;
      *(float4*)(dst + (size_t)j * C_ + 256 + lane * 4) = v1;
    }
  }
}

// zero block: 32 output rows of one batch, zero those >= total
__device__ __forceinline__ void expand_zero_block(const int* __restrict__ csum,
                                                  float* __restrict__ res,
                                                  int z, int tid) {
  const int b  = z >> 6;
  const int t0 = (z & 63) << 5;
  const int total = csum[b * T_ + 255];
  const float4 z4 = make_float4(0.f, 0.f, 0.f, 0.f);
  const int half = tid >> 7, c4 = tid & 127;
#pragma unroll
  for (int rr = half; rr < 32; rr += 2) {
    const int r = t0 + rr;
    if (r >= total)
      *(float4*)(res + ((size_t)b * TOUT_ + r) * C_ + c4 * 4) = z4;
  }
}

// ---------------------------------------------------------------------------
// 1) prep: cvt_x_pad (0..4127) + cvt W1 (4128..4895) + csum (4896..4927)
// ---------------------------------------------------------------------------
__global__ __launch_bounds__(256) void prep_kernel(const float* __restrict__ X,
                                                   const float* __restrict__ W1,
                                                   const int* __restrict__ dur,
                                                   __hip_bfloat16* __restrict__ xpad,
                                                   __hip_bfloat16* __restrict__ hpad,
                                                   __hip_bfloat16* __restrict__ Wt1,
                                                   int* __restrict__ csum) {
  __shared__ float tile[32 * 33];
  const int tid = threadIdx.x;
  if (blockIdx.x >= 4896) {
    csum_block(dur, csum, blockIdx.x - 4896, tid, (int*)tile);
    return;
  }
  if (blockIdx.x >= 4128) {
    const int id = blockIdx.x - 4128;       // 0..767
    wt_convert_block(W1, Wt1, (id % 48) * 32, (id / 48) * 32, tid, tile);
    return;
  }
  const int row = blockIdx.x * 2 + (tid >> 7);   // 0..8255
  const int b = row / TP_;
  const int t = row - b * TP_;
  const int c = (tid & 127) * 4;
  __hip_bfloat16* dst = xpad + (size_t)row * C_ + c;
  if (t == 0 || t == TP_ - 1) {
    ushort4 zz = make_ushort4(0, 0, 0, 0);
    *(ushort4*)dst = zz;
    *(ushort4*)(hpad + (size_t)row * C_ + c) = zz;
    return;
  }
  const float4 v = *(const float4*)(X + (size_t)(b * T_ + t - 1) * C_ + c);
  union { __hip_bfloat16 h[4]; ushort4 u; } o;
  o.h[0] = __float2bfloat16(v.x);
  o.h[1] = __float2bfloat16(v.y);
  o.h[2] = __float2bfloat16(v.z);
  o.h[3] = __float2bfloat16(v.w);
  *(ushort4*)dst = o.u;
}

// ---------------------------------------------------------------------------
// 2) heterogeneous: conv GEMM (0..511) || expand units (512..1791)
//    || optional W2 transpose (1792..2559, first dispatch only)
//    conv: 64(M)x128(N) tile, BK=32, 48 K-steps, 3-buffer LDS ring,
//    counted-vmcnt software pipeline (prefetch depth 2, never drains to 0
//    in the main loop).
// ---------------------------------------------------------------------------
__global__ __launch_bounds__(256) void conv_expand_kernel(
    const __hip_bfloat16* __restrict__ Apad,   // [32*258, 512]
    const __hip_bfloat16* __restrict__ Wt,     // [512, 1536]
    const float* __restrict__ bias,            // [512]
    float* __restrict__ Y,                     // [8192, 512]
    const float* __restrict__ X,               // f32 input (for expand)
    const int* __restrict__ csum,
    float* __restrict__ res,
    const float* __restrict__ W2,              // may be null
    __hip_bfloat16* __restrict__ Wt2,          // may be null
    int ex_base) {
  __shared__ __hip_bfloat16 smA[3][2048];      // 12 KB
  __shared__ __hip_bfloat16 smB[3][4096];      // 24 KB

  const int tid = threadIdx.x;

  if (blockIdx.x >= 1792) {                    // W2 transpose ride-along
    const int id = blockIdx.x - 1792;          // 0..767
    wt_convert_block(W2, Wt2, (id % 48) * 32, (id / 48) * 32, tid, (float*)smA);
    return;
  }
  if (blockIdx.x >= 512) {                     // expand ride-along
    const int u = ex_base + (blockIdx.x - 512);
    if (u < 512) expand_copy_block(X, csum, res, u, tid);
    else         expand_zero_block(csum, res, u - 512, tid);
    return;
  }

  // ---- conv GEMM path ----
  const int lane = tid & 63;
  const int wid  = tid >> 6;
  const int cid  = blockIdx.x;
  const int n0 = (cid & 3) << 7;
  const int m0 = (cid >> 2) << 6;
  const int b  = m0 >> 8;
  const int t0 = m0 & 255;
  const int wn = wid << 5;

  const int ra = tid & 63;
  const int ga = tid >> 6;
  const __hip_bfloat16* arow = Apad + (size_t)(b * TP_ + t0 + ra) * C_;
  const int rb = tid & 127;
  const int gb = tid >> 7;
  const __hip_bfloat16* brow = Wt + (size_t)(n0 + rb) * K_;

  f32x4 acc[4][2] = {};

  // 3 GLL16 per stage per thread -> 3 vmem insts per wave per stage
  auto stage = [&](int buf, int k0) {
    const int kw = k0 >> 9;
    const int c0 = k0 & 511;
    GLL16(arow + kw * C_ + c0 + (ga << 3), &smA[buf][tid << 3]);
    GLL16(brow + k0 + (gb << 3), &smB[buf][tid << 3]);
    GLL16(brow + k0 + ((gb + 2) << 3), &smB[buf][(tid << 3) + 2048]);
  };

  auto compute = [&](int buf) {
    const __hip_bfloat16* As = smA[buf];
    const __hip_bfloat16* Bs = smB[buf];
    const int g   = lane >> 4;
    const int r15 = lane & 15;
    bf16x8 aF[4], bF[2];
#pragma unroll
    for (int i = 0; i < 4; ++i)
      aF[i] = *(const bf16x8*)(As + (g << 9) + (((i << 4) + r15) << 3));
#pragma unroll
    for (int i = 0; i < 2; ++i)
      bF[i] = *(const bf16x8*)(Bs + (g << 10) + ((wn + (i << 4) + r15) << 3));
#pragma unroll
    for (int mi = 0; mi < 4; ++mi)
#pragma unroll
      for (int ni = 0; ni < 2; ++ni)
        acc[mi][ni] = __builtin_amdgcn_mfma_f32_16x16x32_bf16(
            aF[mi], bF[ni], acc[mi][ni], 0, 0, 0);
  };

  // prologue: prefetch 3 tiles (9 vmem in flight per wave)
  stage(0, 0);
  stage(1, 32);
  stage(2, 64);

  int buf = 0;
  // main loop: tiles 0..44; stage tiles 3..47; vmcnt never drains below 6
  for (int s = 0; s < 45; ++s) {
    asm volatile("s_waitcnt vmcnt(6)" ::: "memory");   // oldest tile's 3 loads done
    __builtin_amdgcn_sched_barrier(0);
    __builtin_amdgcn_s_barrier();                      // all waves: tile ready
    compute(buf);
    asm volatile("s_waitcnt lgkmcnt(0)" ::: "memory"); // my ds_reads retired
    __builtin_amdgcn_s_barrier();                      // all waves: done reading
    stage(buf, (s + 3) << 5);                          // overwrite oldest buf
    buf = (buf == 2) ? 0 : buf + 1;
  }
  // tail: tiles 45,46,47 — drain 6 -> 3 -> 0
  asm volatile("s_waitcnt vmcnt(6)" ::: "memory");
  __builtin_amdgcn_sched_barrier(0);
  __builtin_amdgcn_s_barrier();
  compute(buf);
  buf = (buf == 2) ? 0 : buf + 1;
  asm volatile("s_waitcnt vmcnt(3)" ::: "memory");
  __builtin_amdgcn_sched_barrier(0);
  __builtin_amdgcn_s_barrier();
  compute(buf);
  buf = (buf == 2) ? 0 : buf + 1;
  asm volatile("s_waitcnt vmcnt(0)" ::: "memory");
  __builtin_amdgcn_sched_barrier(0);
  __builtin_amdgcn_s_barrier();
  compute(buf);

  const int cn_base = n0 + wn + (lane & 15);
  const int rm_base = m0 + ((lane >> 4) << 2);
#pragma unroll
  for (int ni = 0; ni < 2; ++ni) {
    const int cn = cn_base + (ni << 4);
    const float bb = bias[cn];
#pragma unroll
    for (int mi = 0; mi < 4; ++mi) {
#pragma unroll
      for (int rq = 0; rq < 4; ++rq) {
        const int rm = rm_base + (mi << 4) + rq;
        Y[(size_t)rm * H_ + cn] = acc[mi][ni][rq] + bb;
      }
    }
  }
}

// ---------------------------------------------------------------------------
// 3) LayerNorm + ReLU, f32 in -> bf16 out written into padded layout
// ---------------------------------------------------------------------------
__global__ __launch_bounds__(256) void ln_relu_pad_kernel(const float* __restrict__ in,
                                                          const float* __restrict__ g,
                                                          const float* __restrict__ beta,
                                                          __hip_bfloat16* __restrict__ outpad) {
  const int wave = threadIdx.x >> 6;
  const int lane = threadIdx.x & 63;
  const int row  = blockIdx.x * 4 + wave;   // 0..8191
  const float* r = in + (size_t)row * H_;

  const float4 v0 = *(const float4*)(r + lane * 4);
  const float4 v1 = *(const float4*)(r + 256 + lane * 4);

  float s = v0.x + v0.y + v0.z + v0.w + v1.x + v1.y + v1.z + v1.w;
  float q = v0.x * v0.x + v0.y * v0.y + v0.z * v0.z + v0.w * v0.w +
            v1.x * v1.x + v1.y * v1.y + v1.z * v1.z + v1.w * v1.w;
#pragma unroll
  for (int off = 32; off; off >>= 1) {
    s += __shfl_xor(s, off);
    q += __shfl_xor(q, off);
  }
  const float mu  = s * (1.0f / 512.0f);
  const float var = q * (1.0f / 512.0f) - mu * mu;
  const float rs  = rsqrtf(var + EPS_);

  const float4 g0 = *(const float4*)(g + lane * 4);
  const float4 g1 = *(const float4*)(g + 256 + lane * 4);
  const float4 e0 = *(const float4*)(beta + lane * 4);
  const float4 e1 = *(const float4*)(beta + 256 + lane * 4);

  union { __hip_bfloat16 h[4]; ushort4 u; } o0, o1;
  o0.h[0] = __float2bfloat16(fmaxf(0.f, (v0.x - mu) * rs * g0.x + e0.x));
  o0.h[1] = __float2bfloat16(fmaxf(0.f, (v0.y - mu) * rs * g0.y + e0.y));
  o0.h[2] = __float2bfloat16(fmaxf(0.f, (v0.z - mu) * rs * g0.z + e0.z));
  o0.h[3] = __float2bfloat16(fmaxf(0.f, (v0.w - mu) * rs * g0.w + e0.w));
  o1.h[0] = __float2bfloat16(fmaxf(0.f, (v1.x - mu) * rs * g1.x + e1.x));
  o1.h[1] = __float2bfloat16(fmaxf(0.f, (v1.y - mu) * rs * g1.y + e1.y));
  o1.h[2] = __float2bfloat16(fmaxf(0.f, (v1.z - mu) * rs * g1.z + e1.z));
  o1.h[3] = __float2bfloat16(fmaxf(0.f, (v1.w - mu) * rs * g1.w + e1.w));

  const int bq = row >> 8, t = row & 255;
  __hip_bfloat16* w = outpad + (size_t)(bq * TP_ + t + 1) * H_;
  *(ushort4*)(w + lane * 4)       = o0.u;
  *(ushort4*)(w + 256 + lane * 4) = o1.u;
}

// ---------------------------------------------------------------------------
// 4) LayerNorm + ReLU + linear head fused
// ---------------------------------------------------------------------------
__global__ __launch_bounds__(256) void ln_relu_linear_kernel(const float* __restrict__ in,
                                                             const float* __restrict__ g,
                                                             const float* __restrict__ beta,
                                                             const float* __restrict__ Wl,
                                                             const float* __restrict__ bl,
                                                             float* __restrict__ out) {
  const int wave = threadIdx.x >> 6;
  const int lane = threadIdx.x & 63;
  const int row  = blockIdx.x * 4 + wave;
  const float* r = in + (size_t)row * H_;

  const float4 v0 = *(const float4*)(r + lane * 4);
  const float4 v1 = *(const float4*)(r + 256 + lane * 4);

  float s = v0.x + v0.y + v0.z + v0.w + v1.x + v1.y + v1.z + v1.w;
  float q = v0.x * v0.x + v0.y * v0.y + v0.z * v0.z + v0.w * v0.w +
            v1.x * v1.x + v1.y * v1.y + v1.z * v1.z + v1.w * v1.w;
#pragma unroll
  for (int off = 32; off; off >>= 1) {
    s += __shfl_xor(s, off);
    q += __shfl_xor(q, off);
  }
  const float mu  = s * (1.0f / 512.0f);
  const float var = q * (1.0f / 512.0f) - mu * mu;
  const float rs  = rsqrtf(var + EPS_);

  const float4 g0 = *(const float4*)(g + lane * 4);
  const float4 g1 = *(const float4*)(g + 256 + lane * 4);
  const float4 e0 = *(const float4*)(beta + lane * 4);
  const float4 e1 = *(const float4*)(beta + 256 + lane * 4);
  const float4 w0 = *(const float4*)(Wl + lane * 4);
  const float4 w1 = *(const float4*)(Wl + 256 + lane * 4);

  float sd = 0.f;
  sd += fmaxf(0.f, (v0.x - mu) * rs * g0.x + e0.x) * w0.x;
  sd += fmaxf(0.f, (v0.y - mu) * rs * g0.y + e0.y) * w0.y;
  sd += fmaxf(0.f, (v0.z - mu) * rs * g0.z + e0.z) * w0.z;
  sd += fmaxf(0.f, (v0.w - mu) * rs * g0.w + e0.w) * w0.w;
  sd += fmaxf(0.f, (v1.x - mu) * rs * g1.x + e1.x) * w1.x;
  sd += fmaxf(0.f, (v1.y - mu) * rs * g1.y + e1.y) * w1.y;
  sd += fmaxf(0.f, (v1.z - mu) * rs * g1.z + e1.z) * w1.z;
  sd += fmaxf(0.f, (v1.w - mu) * rs * g1.w + e1.w) * w1.w;
#pragma unroll
  for (int off = 32; off; off >>= 1) sd += __shfl_xor(sd, off);

  if (lane == 0) out[row] = sd + bl[0];
}

// ---------------------------------------------------------------------------
extern "C" void kernel_launch(void* const* d_in, const int* in_sizes, int n_in,
                              void* d_out, int out_size, void* d_ws, size_t ws_size,
                              hipStream_t stream) {
  const float* x     = (const float*)d_in[0];
  const int*   dur   = (const int*)d_in[1];
  const float* W1    = (const float*)d_in[2];
  const float* b1    = (const float*)d_in[3];
  const float* g1    = (const float*)d_in[4];
  const float* beta1 = (const float*)d_in[5];
  const float* W2    = (const float*)d_in[6];
  const float* b2    = (const float*)d_in[7];
  const float* g2    = (const float*)d_in[8];
  const float* beta2 = (const float*)d_in[9];
  const float* Wl    = (const float*)d_in[10];
  const float* bl    = (const float*)d_in[11];

  float* out = (float*)d_out;
  float* res    = out;                              // [B, TOUT, C]
  float* loglen = out + (size_t)B_ * TOUT_ * C_;    // [B, T]

  char* ws = (char*)d_ws;
  __hip_bfloat16* xpad = (__hip_bfloat16*)ws;                       // 8.45 MB
  __hip_bfloat16* hpad = xpad + (size_t)B_ * TP_ * C_;              // 8.45 MB
  __hip_bfloat16* Wt1  = hpad + (size_t)B_ * TP_ * C_;              // 1.57 MB
  __hip_bfloat16* Wt2  = Wt1 + (size_t)H_ * K_;                     // 1.57 MB
  float* tmp1 = (float*)(Wt2 + (size_t)H_ * K_);                    // 16.8 MB
  int*   csum = (int*)(tmp1 + (size_t)B_ * T_ * H_);                // 32 KB

  prep_kernel<<<4928, 256, 0, stream>>>(x, W1, dur, xpad, hpad, Wt1, csum);

  // conv1 || expand units 0..1279 (all copies + zeros 0..767) || W2 transpose
  conv_expand_kernel<<<2560, 256, 0, stream>>>(xpad, Wt1, b1, tmp1,
                                               x, csum, res, W2, Wt2, 0);
  ln_relu_pad_kernel<<<B_ * T_ / 4, 256, 0, stream>>>(tmp1, g1, beta1, hpad);

  // conv2 || expand units 1280..2559 (zeros 768..2047)
  conv_expand_kernel<<<1792, 256, 0, stream>>>(hpad, Wt2, b2, tmp1,
                                               x, csum, res, nullptr, nullptr, 1280);
  ln_relu_linear_kernel<<<B_ * T_ / 4, 256, 0, stream>>>(tmp1, g2, beta2, Wl, bl, loglen);
}